// Round 4
// baseline (428.002 us; speedup 1.0000x reference)
//
#include <hip/hip_runtime.h>
#include <stdint.h>

typedef unsigned short u16;
typedef short short8 __attribute__((ext_vector_type(8)));
typedef float f32x4 __attribute__((ext_vector_type(4)));

// Problem sizes: B=16384, D=768, E=124 (pad 128), C=6, E*C=744 (pad 768)
#define NB 16384

// ---- workspace layout (bytes) ----
#define OFF_XHI      0ull            // bf16 [16384][768]
#define OFF_XLO      25165824ull     // bf16 [16384][768]
#define OFF_LCLS     0ull            // aliases XHI: bf16 [16384][768] class logits (cols 0..743 real)
#define OFF_LWE      25165824ull     // aliases XLO: f32 [16384][128] which_expert
#define OFF_LEW      33554432ull     // f32 [16384][128] expert-weight logits
#define OFF_BT1      50331648ull     // bf16 [1536][768]  (cls_w1^T ; ew_w1^T)
#define OFF_BTWE_HI  52690944ull     // bf16 [768][768]
#define OFF_BTWE_LO  53870592ull
#define OFF_BT2CLS   55050240ull     // bf16 [768][768] (744 real rows, padded w/ 0)
#define OFF_BT2EW    56229888ull     // bf16 [128][768]
#define OFF_BT2WE_HI 56426496ull
#define OFF_BT2WE_LO 56623104ull
#define OFF_B1CE     56819712ull     // f32 [1536]
#define OFF_B1WE     56825856ull     // f32 [768]
#define OFF_B2CLS    56828928ull     // f32 [768]
#define OFF_B2EW     56832000ull     // f32 [128]
#define OFF_B2WE     56832512ull     // f32 [128]
#define OFF_HCLSEW   56833024ull     // bf16 [16384][1536] gelu(h) for cls|ew
#define OFF_HWE_HI   107164672ull    // bf16 [16384][768]
#define OFF_HWE_LO   132330496ull    // bf16 [16384][768]
#define WS_NEED      157496320ull

__device__ __forceinline__ u16 f2bf(float f) {          // RNE f32->bf16
  uint32_t u = __float_as_uint(f);
  u += 0x7fffu + ((u >> 16) & 1u);
  return (u16)(u >> 16);
}
__device__ __forceinline__ float bf2f(u16 h) {
  return __uint_as_float(((uint32_t)h) << 16);
}
__device__ __forceinline__ void g2l16(const u16* g, u16* l) {
  // async global->LDS, 16B/lane; LDS dest = wave-uniform base + lane*16 (HW rule)
  __builtin_amdgcn_global_load_lds(
      (__attribute__((address_space(1))) void*)(u16*)g,
      (__attribute__((address_space(3))) void*)l, 16, 0, 0);
}

// ---------------- merged prep: cvt_x split + weight transposes + bias concat ----------------
// grid layout: [0,12288) cvt_x ; [12288,13152) transpose (12x12x6) ; [13152,13165) bias
__global__ void prep_all(
    const float* __restrict__ x, u16* __restrict__ xhi, u16* __restrict__ xlo,
    const float* __restrict__ cls_w1, const float* __restrict__ ew_w1,
    const float* __restrict__ we_w1,  const float* __restrict__ cls_w2,
    const float* __restrict__ ew_w2,  const float* __restrict__ we_w2,
    u16* BT1, u16* BTwe_hi, u16* BTwe_lo,
    u16* BT2cls, u16* BT2ew, u16* BT2we_hi, u16* BT2we_lo,
    const float* __restrict__ cls_b1, const float* __restrict__ ew_b1,
    const float* __restrict__ we_b1,  const float* __restrict__ cls_b2,
    const float* __restrict__ ew_b2,  const float* __restrict__ we_b2,
    float* b1ce, float* b1we, float* b2cls, float* b2ew, float* b2we) {
  __shared__ float t[64][65];
  const int bid = blockIdx.x;
  if (bid < 12288) {                       // ---- x -> (hi,lo) bf16 split
    int i = bid * 256 + threadIdx.x;       // 12288*256 = 16384*768/4 exact
    float4 v = ((const float4*)x)[i];
    ushort4 h, l;
    h.x = f2bf(v.x); l.x = f2bf(v.x - bf2f(h.x));
    h.y = f2bf(v.y); l.y = f2bf(v.y - bf2f(h.y));
    h.z = f2bf(v.z); l.z = f2bf(v.z - bf2f(h.z));
    h.w = f2bf(v.w); l.w = f2bf(v.w - bf2f(h.w));
    ((ushort4*)xhi)[i] = h;
    ((ushort4*)xlo)[i] = l;
    return;
  }
  if (bid < 13152) {                       // ---- LDS-tiled transpose W[768][N] -> BT[Npad][768]
    const int idx = bid - 12288;
    const int bx = idx % 12, by = (idx / 12) % 12, bz = idx / 144;
    const float* src; int N; u16* dhi; u16* dlo = nullptr;
    switch (bz) {
      case 0: src = cls_w1; N = 768; dhi = BT1; break;
      case 1: src = ew_w1;  N = 768; dhi = BT1 + 768 * 768; break;
      case 2: src = we_w1;  N = 768; dhi = BTwe_hi; dlo = BTwe_lo; break;
      case 3: src = cls_w2; N = 744; dhi = BT2cls; break;
      case 4: src = ew_w2;  N = 124; dhi = BT2ew; break;
      default: src = we_w2; N = 124; dhi = BT2we_hi; dlo = BT2we_lo; break;
    }
    const int Npad = (N + 127) & ~127;
    const int n0 = by * 64;
    if (n0 >= Npad) return;
    const int k0 = bx * 64;
    const int tx = threadIdx.x & 63, tg = threadIdx.x >> 6;
#pragma unroll
    for (int r = 0; r < 16; ++r) {
      int k = tg * 16 + r;
      int n = n0 + tx;
      t[k][tx] = (n < N) ? src[(size_t)(k0 + k) * N + n] : 0.f;   // coalesced read
    }
    __syncthreads();
#pragma unroll
    for (int r = 0; r < 16; ++r) {
      int n = n0 + tg * 16 + r;
      if (n < Npad) {
        float v = t[tx][tg * 16 + r];
        u16 h = f2bf(v);
        dhi[(size_t)n * 768 + k0 + tx] = h;                       // coalesced write
        if (dlo) dlo[(size_t)n * 768 + k0 + tx] = f2bf(v - bf2f(h));
      }
    }
    return;
  }
  // ---- bias concat/pad: 13 blocks * 256 = 3328 = 1536+768+768+128+128 exact
  int id = (bid - 13152) * 256 + threadIdx.x;
  if (id < 1536) { b1ce[id] = (id < 768) ? cls_b1[id] : ew_b1[id - 768]; return; }
  id -= 1536;
  if (id < 768) { b1we[id] = we_b1[id]; return; }
  id -= 768;
  if (id < 768) { b2cls[id] = (id < 744) ? cls_b2[id] : 0.f; return; }
  id -= 768;
  if (id < 128) { b2ew[id] = (id < 124) ? ew_b2[id] : 0.f; return; }
  id -= 128;
  if (id < 128) { b2we[id] = (id < 124) ? we_b2[id] : 0.f; return; }
}

// ---------------- GEMM core: (NW*64)x128 tile, BK=64, 2*NW waves in 4x2/2x2, XOR-swizzled LDS ----------------
// LDS: logical (row, c8) at physical c8p = c8 ^ (row&7) -> conflict-free ds_read_b128 (R2: 0 conflicts).
// Staging permutes the *global* source per lane since global_load_lds's LDS side is rigid.
template <int NW>
__device__ __forceinline__ void gemm_core(
    const u16* A0, const u16* A1, const u16* A2, int lda,
    const u16* B0, const u16* B1, const u16* B2,   // pre-offset by bn*K
    int npass, int K, int bm, int tid, u16* sA, u16* sB, f32x4 acc[4][4]) {
  const int lane = tid & 63;
  const int wv = tid >> 6;                         // 0..2*NW-1
  const int wr = wv >> 1, wc = wv & 1;
  const int sr = lane >> 3;                        // staging row within 8-row group
  const int sc = (((lane & 7) ^ sr) << 3);         // swizzled source col group
  const int BROWS = 64 / NW;                       // B rows staged per wave
  for (int p = 0; p < npass; ++p) {
    const u16* A = (p == 0) ? A0 : ((p == 1) ? A1 : A2);
    const u16* Bp = (p == 0) ? B0 : ((p == 1) ? B1 : B2);
    const u16* gA = A + (size_t)(bm + wv * 32 + sr) * lda + sc;
    const u16* gB = Bp + (size_t)(wv * BROWS + sr) * K + sc;
    u16* lA = sA + (wv * 32) * 64;
    u16* lB = sB + (wv * BROWS) * 64;
    for (int kt = 0; kt < K; kt += 64) {
#pragma unroll
      for (int s = 0; s < 4; ++s)
        g2l16(gA + (size_t)(s * 8) * lda + kt, lA + s * 8 * 64);
#pragma unroll
      for (int s = 0; s < BROWS / 8; ++s)
        g2l16(gB + (size_t)(s * 8) * K + kt, lB + s * 8 * 64);
      __syncthreads();
#pragma unroll
      for (int ks = 0; ks < 2; ++ks) {
        const int co = ((ks * 4 + (lane >> 4)) ^ (lane & 7)) * 8;  // row&7 == lane&7 for all frags
        short8 av[4], bv[4];
#pragma unroll
        for (int i = 0; i < 4; i++)
          av[i] = *(const short8*)(sA + (wr * 64 + i * 16 + (lane & 15)) * 64 + co);
#pragma unroll
        for (int j = 0; j < 4; j++)
          bv[j] = *(const short8*)(sB + (wc * 64 + j * 16 + (lane & 15)) * 64 + co);
#pragma unroll
        for (int i = 0; i < 4; i++)
#pragma unroll
          for (int j = 0; j < 4; j++)
            acc[i][j] = __builtin_amdgcn_mfma_f32_16x16x32_bf16(av[i], bv[j], acc[i][j], 0, 0, 0);
      }
      __syncthreads();
    }
  }
}

// XCD/L2 swizzle for 128-row tiles: xcd=bid&7 owns 16 row-chunks; 8-row sub-bands, rows fastest.
__device__ __forceinline__ void decode_bid(int bid, int NC, int& bm, int& bn) {
  const int xcd = bid & 7, slot = bid >> 3;
  const int per = NC << 3;
  const int sub = slot / per, rem = slot - sub * per;
  const int colu = rem >> 3, rowIn = rem & 7;
  bm = ((xcd << 4) + (sub << 3) + rowIn) << 7;
  bn = colu << 7;
}

// MODE 0: gelu -> bf16    MODE 2: gelu -> bf16 hi + bf16 lo
// NW=4: 256x128 tile, 512 thr, 48KB LDS -> 3 blocks/CU (24 waves/CU), 768 blocks = 1 exact round.
// NW=2: 128x128 tile, 256 thr, 32KB LDS -> 5 blocks/CU capacity (slack absorbs dispatch imbalance;
//       R3 showed padding this to 3/CU regresses 80->116 us).
template <int MODE, int NW>
__global__ __launch_bounds__(NW * 128, NW == 4 ? 3 : 4) void gemm_k(
    const u16* A0, const u16* A1, const u16* A2, int lda,
    const u16* B0, const u16* B1, const u16* B2,
    int npass, int K, const float* __restrict__ bias,
    void* out0, void* out1, int ldc, int NC) {
  __shared__ u16 sA[NW * 64 * 64];
  __shared__ u16 sB[128 * 64];
  const int tid = threadIdx.x;
  const int lane = tid & 63;
  const int wr = (tid >> 6) >> 1, wc = (tid >> 6) & 1;
  int bm, bn;
  if (NW == 4) {                           // 64 row-chunks of 256: 8 per XCD, rows fastest
    const int xcd = blockIdx.x & 7, rem = blockIdx.x >> 3;
    bm = ((xcd << 3) + (rem & 7)) << 8;
    bn = (rem >> 3) << 7;
  } else {
    decode_bid(blockIdx.x, NC, bm, bn);
  }

  f32x4 acc[4][4];
#pragma unroll
  for (int i = 0; i < 4; i++)
#pragma unroll
    for (int j = 0; j < 4; j++) acc[i][j] = f32x4{0.f, 0.f, 0.f, 0.f};

  const size_t bo = (size_t)bn * K;
  gemm_core<NW>(A0, A1, A2, lda, B0 + bo, B1 ? B1 + bo : nullptr, B2 ? B2 + bo : nullptr,
                npass, K, bm, tid, sA, sB, acc);

  // C/D layout: col=lane&15, row=(lane>>4)*4+r  [verified m89/m91]
#pragma unroll
  for (int j = 0; j < 4; j++) {
    const int col = bn + wc * 64 + j * 16 + (lane & 15);
    const float bs = bias[col];
#pragma unroll
    for (int i = 0; i < 4; i++) {
      const int row0 = bm + wr * 64 + i * 16 + (lane >> 4) * 4;
#pragma unroll
      for (int r = 0; r < 4; r++) {
        float v = acc[i][j][r] + bs;
        const size_t idx = (size_t)(row0 + r) * ldc + col;
        float g = 0.5f * v * (1.0f + erff(v * 0.70710678118654752f));  // exact GELU
        u16 h = f2bf(g);
        ((u16*)out0)[idx] = h;
        if (MODE == 2) ((u16*)out1)[idx] = f2bf(g - bf2f(h));
      }
    }
  }
}

// fused fc2, HEAVY-FIRST bid order:
//   bid [0,128)    -> we 3-pass split (3x duration -> dispatch first, kills the tail)
//   bid [128,256)  -> ew
//   bid [256,1024) -> cls (6 col-tiles)
__global__ __launch_bounds__(256, 4) void gemm2_fused(
    const u16* __restrict__ h_cls,                  // [16384][1536]: cls cols 0..767, ew cols 768..1535
    const u16* __restrict__ hwe_hi, const u16* __restrict__ hwe_lo,
    const u16* __restrict__ BT2cls, const u16* __restrict__ BT2ew,
    const u16* __restrict__ BT2we_hi, const u16* __restrict__ BT2we_lo,
    const float* __restrict__ b2cls, const float* __restrict__ b2ew,
    const float* __restrict__ b2we,
    u16* __restrict__ Lcls, float* __restrict__ Lew, float* __restrict__ Lwe) {
  __shared__ u16 sA[128 * 64];
  __shared__ u16 sB[128 * 64];
  const int tid = threadIdx.x;
  const int lane = tid & 63;
  const int wr = (tid >> 6) >> 1, wc = (tid >> 6) & 1;

  f32x4 acc[4][4];
#pragma unroll
  for (int i = 0; i < 4; i++)
#pragma unroll
    for (int j = 0; j < 4; j++) acc[i][j] = f32x4{0.f, 0.f, 0.f, 0.f};

  const int bid = blockIdx.x;
  if (bid >= 256) {                        // ---- cls: 768 blocks, 6 col-tiles
    int bm, bn;
    decode_bid(bid - 256, 6, bm, bn);
    gemm_core<2>(h_cls, nullptr, nullptr, 1536, BT2cls + (size_t)bn * 768, nullptr, nullptr,
                 1, 768, bm, tid, sA, sB, acc);
#pragma unroll
    for (int j = 0; j < 4; j++) {
      const int col = bn + wc * 64 + j * 16 + (lane & 15);
      const float bs = b2cls[col];
#pragma unroll
      for (int i = 0; i < 4; i++) {
        const int row0 = bm + wr * 64 + i * 16 + (lane >> 4) * 4;
#pragma unroll
        for (int r = 0; r < 4; r++)
          Lcls[(size_t)(row0 + r) * 768 + col] = f2bf(acc[i][j][r] + bs);
      }
    }
  } else {                                 // ---- heavy: we [0,128), ew [128,256)
    const bool is_we = (bid < 128);
    const int r = is_we ? bid : bid - 128;
    const int bm = (((r & 7) << 4) + (r >> 3)) << 7;   // xcd owns 16 row-chunks
    if (is_we)
      gemm_core<2>(hwe_hi, hwe_lo, hwe_hi, 768, BT2we_hi, BT2we_hi, BT2we_lo,
                   3, 768, bm, tid, sA, sB, acc);
    else
      gemm_core<2>(h_cls + 768, nullptr, nullptr, 1536, BT2ew, nullptr, nullptr,
                   1, 768, bm, tid, sA, sB, acc);
    float* o = is_we ? Lwe : Lew;
    const float* bp = is_we ? b2we : b2ew;
#pragma unroll
    for (int j = 0; j < 4; j++) {
      const int col = wc * 64 + j * 16 + (lane & 15);
      const float bs = bp[col];
#pragma unroll
      for (int i = 0; i < 4; i++) {
        const int row0 = bm + wr * 64 + i * 16 + (lane >> 4) * 4;
#pragma unroll
        for (int r2 = 0; r2 < 4; r2++)
          o[(size_t)(row0 + r2) * 128 + col] = acc[i][j][r2] + bs;
      }
    }
  }
}

// ---------------- finalize: rank-select mask (== reference threshold), softmaxes, mixture ----------------
// keep_i  <=>  which_i >= n-th largest  <=>  #{j : w_j > w_i} < n   (ties keep both, same as ref)
__global__ __launch_bounds__(256) void finalize(
    const u16* __restrict__ Lcls,   // bf16 [B][768], expert e at cols e*6..e*6+5
    const float* __restrict__ Lwe,  // f32 [B][128]
    const float* __restrict__ Lew,  // f32 [B][128]
    const int* __restrict__ nexp, float* __restrict__ out) {
  const int bid = blockIdx.x;
  const int g = ((bid & 7) << 9) + (bid >> 3);      // XCD band matches gemm2's row mapping
  const int b = (g << 2) + (int)(threadIdx.x >> 6); // 4 rows/block, one wave each
  const int lane = threadIdx.x & 63;
  const float NEG = -3.0e38f;
  const float w0 = (lane < 124) ? Lwe[(size_t)b * 128 + lane] : NEG;
  const float w1 = (lane < 60) ? Lwe[(size_t)b * 128 + 64 + lane] : NEG;
  int r0 = 0, r1 = 0;
#pragma unroll
  for (int j = 0; j < 64; ++j) {
    float v = __shfl(w0, j, 64);
    r0 += (v > w0); r1 += (v > w1);
  }
#pragma unroll
  for (int j = 0; j < 64; ++j) {
    float v = __shfl(w1, j, 64);
    r0 += (v > w0); r1 += (v > w1);
  }
  int n = nexp[b];
  n = n < 1 ? 1 : (n > 124 ? 124 : n);
  const bool k0 = (lane < 124) && (r0 < n);
  const bool k1 = (lane < 60) && (r1 < n);
  float l0 = k0 ? Lew[(size_t)b * 128 + lane] : NEG;
  float l1 = k1 ? Lew[(size_t)b * 128 + 64 + lane] : NEG;
  float mx = fmaxf(l0, l1);
#pragma unroll
  for (int o = 32; o > 0; o >>= 1) mx = fmaxf(mx, __shfl_xor(mx, o, 64));
  float e0 = k0 ? __expf(l0 - mx) : 0.f;
  float e1 = k1 ? __expf(l1 - mx) : 0.f;
  float S = e0 + e1;
#pragma unroll
  for (int o = 32; o > 0; o >>= 1) S += __shfl_xor(S, o, 64);
  float a0 = 0, a1 = 0, a2 = 0, a3 = 0, a4 = 0, a5 = 0;
#pragma unroll
  for (int h = 0; h < 2; ++h) {
    int e = lane + h * 64;
    float we = h ? e1 : e0;
    if (we > 0.f) {
      const u16* lp = Lcls + (size_t)b * 768 + e * 6;
      float c0 = bf2f(lp[0]), c1 = bf2f(lp[1]), c2 = bf2f(lp[2]);
      float c3 = bf2f(lp[3]), c4 = bf2f(lp[4]), c5 = bf2f(lp[5]);
      float m = fmaxf(fmaxf(fmaxf(c0, c1), fmaxf(c2, c3)), fmaxf(c4, c5));
      float p0 = __expf(c0 - m), p1 = __expf(c1 - m), p2 = __expf(c2 - m);
      float p3 = __expf(c3 - m), p4 = __expf(c4 - m), p5 = __expf(c5 - m);
      float inv = we / (p0 + p1 + p2 + p3 + p4 + p5);
      a0 += p0 * inv; a1 += p1 * inv; a2 += p2 * inv;
      a3 += p3 * inv; a4 += p4 * inv; a5 += p5 * inv;
    }
  }
#pragma unroll
  for (int o = 32; o > 0; o >>= 1) {
    a0 += __shfl_xor(a0, o, 64); a1 += __shfl_xor(a1, o, 64);
    a2 += __shfl_xor(a2, o, 64); a3 += __shfl_xor(a3, o, 64);
    a4 += __shfl_xor(a4, o, 64); a5 += __shfl_xor(a5, o, 64);
  }
  if (lane < 6) {
    float v = (lane == 0) ? a0 : (lane == 1) ? a1 : (lane == 2) ? a2
              : (lane == 3) ? a3 : (lane == 4) ? a4 : a5;
    out[(size_t)b * 6 + lane] = v / S;
  }
}

__global__ void fill_sentinel(float* out, int n, float v) {
  int i = blockIdx.x * 256 + threadIdx.x;
  if (i < n) out[i] = v;
}

extern "C" void kernel_launch(void* const* d_in, const int* in_sizes, int n_in,
                              void* d_out, int out_size, void* d_ws, size_t ws_size,
                              hipStream_t stream) {
  const float* x = (const float*)d_in[0];
  const int* nexp = (const int*)d_in[1];
  const float* cls_w1 = (const float*)d_in[2];
  const float* cls_b1 = (const float*)d_in[3];
  const float* cls_w2 = (const float*)d_in[4];
  const float* cls_b2 = (const float*)d_in[5];
  const float* we_w1 = (const float*)d_in[6];
  const float* we_b1 = (const float*)d_in[7];
  const float* we_w2 = (const float*)d_in[8];
  const float* we_b2 = (const float*)d_in[9];
  const float* ew_w1 = (const float*)d_in[10];
  const float* ew_b1 = (const float*)d_in[11];
  const float* ew_w2 = (const float*)d_in[12];
  const float* ew_b2 = (const float*)d_in[13];
  float* out = (float*)d_out;
  char* ws = (char*)d_ws;

  if (ws_size < WS_NEED) {  // diagnosable failure: absmax ~12345
    fill_sentinel<<<(out_size + 255) / 256, 256, 0, stream>>>(out, out_size, 12345.0f);
    return;
  }

  u16* xhi = (u16*)(ws + OFF_XHI);
  u16* xlo = (u16*)(ws + OFF_XLO);
  u16* Lcls = (u16*)(ws + OFF_LCLS);
  float* Lwe = (float*)(ws + OFF_LWE);
  float* Lew = (float*)(ws + OFF_LEW);
  u16* BT1 = (u16*)(ws + OFF_BT1);
  u16* BTwe_hi = (u16*)(ws + OFF_BTWE_HI);
  u16* BTwe_lo = (u16*)(ws + OFF_BTWE_LO);
  u16* BT2cls = (u16*)(ws + OFF_BT2CLS);
  u16* BT2ew = (u16*)(ws + OFF_BT2EW);
  u16* BT2we_hi = (u16*)(ws + OFF_BT2WE_HI);
  u16* BT2we_lo = (u16*)(ws + OFF_BT2WE_LO);
  float* b1ce = (float*)(ws + OFF_B1CE);
  float* b1we = (float*)(ws + OFF_B1WE);
  float* b2cls = (float*)(ws + OFF_B2CLS);
  float* b2ew = (float*)(ws + OFF_B2EW);
  float* b2we = (float*)(ws + OFF_B2WE);
  u16* h_clsew = (u16*)(ws + OFF_HCLSEW);
  u16* h_we_hi = (u16*)(ws + OFF_HWE_HI);
  u16* h_we_lo = (u16*)(ws + OFF_HWE_LO);

  prep_all<<<13165, 256, 0, stream>>>(x, xhi, xlo,
                                      cls_w1, ew_w1, we_w1, cls_w2, ew_w2, we_w2,
                                      BT1, BTwe_hi, BTwe_lo, BT2cls, BT2ew, BT2we_hi, BT2we_lo,
                                      cls_b1, ew_b1, we_b1, cls_b2, ew_b2, we_b2,
                                      b1ce, b1we, b2cls, b2ew, b2we);
  // fc1 cls+ew (N=1536): 256x128 tiles, 512 thr, 48KB LDS -> 3 blocks/CU, 768 blocks = 1 exact round
  gemm_k<0, 4><<<768, 512, 0, stream>>>(xhi, nullptr, nullptr, 768,
                                        BT1, nullptr, nullptr, 1, 768,
                                        b1ce, h_clsew, nullptr, 1536, 12);
  // fc1 we, 3-term split (hi*Whi + lo*Whi + hi*Wlo): 128x128, 32KB LDS (5/CU capacity slack)
  gemm_k<2, 2><<<768, 256, 0, stream>>>(xhi, xlo, xhi, 768,
                                        BTwe_hi, BTwe_hi, BTwe_lo, 3, 768,
                                        b1we, h_we_hi, h_we_lo, 768, 6);
  // fc2 all three heads in one dispatch, heavy (3-pass we) blocks first
  gemm2_fused<<<1024, 256, 0, stream>>>(h_clsew, h_we_hi, h_we_lo,
                                        BT2cls, BT2ew, BT2we_hi, BT2we_lo,
                                        b2cls, b2ew, b2we, Lcls, Lew, Lwe);
  finalize<<<4096, 256, 0, stream>>>(Lcls, Lwe, Lew, nexp, out);
}

// Round 5
// 378.788 us; speedup vs baseline: 1.1299x; 1.1299x over previous
//
#include <hip/hip_runtime.h>
#include <stdint.h>

typedef unsigned short u16;
typedef short short8 __attribute__((ext_vector_type(8)));
typedef float f32x4 __attribute__((ext_vector_type(4)));

// Problem sizes: B=16384, D=768, E=124 (pad 128), C=6, E*C=744 (pad 768)
#define NB 16384

// ---- workspace layout (bytes) ----
#define OFF_XHI      0ull            // bf16 [16384][768]
#define OFF_XLO      25165824ull     // bf16 [16384][768]
#define OFF_LCLS     0ull            // aliases XHI: bf16 [16384][768] class logits (cols 0..743 real)
#define OFF_LWE      25165824ull     // aliases XLO: f32 [16384][128] which_expert
#define OFF_LEW      33554432ull     // f32 [16384][128] expert-weight logits
#define OFF_BT1      50331648ull     // bf16 [1536][768]  (cls_w1^T ; ew_w1^T)
#define OFF_BTWE_HI  52690944ull     // bf16 [768][768]
#define OFF_BTWE_LO  53870592ull
#define OFF_BT2CLS   55050240ull     // bf16 [768][768] (744 real rows, padded w/ 0)
#define OFF_BT2EW    56229888ull     // bf16 [128][768]
#define OFF_BT2WE_HI 56426496ull
#define OFF_BT2WE_LO 56623104ull
#define OFF_B1CE     56819712ull     // f32 [1536]
#define OFF_B1WE     56825856ull     // f32 [768]
#define OFF_B2CLS    56828928ull     // f32 [768]
#define OFF_B2EW     56832000ull     // f32 [128]
#define OFF_B2WE     56832512ull     // f32 [128]
#define OFF_HCLSEW   56833024ull     // bf16 [16384][1536] gelu(h) for cls|ew
#define OFF_HWE_HI   107164672ull    // bf16 [16384][768]
#define OFF_HWE_LO   132330496ull    // bf16 [16384][768]
#define WS_NEED      157496320ull

__device__ __forceinline__ u16 f2bf(float f) {          // RNE f32->bf16
  uint32_t u = __float_as_uint(f);
  u += 0x7fffu + ((u >> 16) & 1u);
  return (u16)(u >> 16);
}
__device__ __forceinline__ float bf2f(u16 h) {
  return __uint_as_float(((uint32_t)h) << 16);
}
__device__ __forceinline__ void g2l16(const u16* g, u16* l) {
  // async global->LDS, 16B/lane; LDS dest = wave-uniform base + lane*16 (HW rule).
  // Global side is a normal per-lane address -> per-lane source permutation is legal.
  __builtin_amdgcn_global_load_lds(
      (__attribute__((address_space(1))) void*)(u16*)g,
      (__attribute__((address_space(3))) void*)l, 16, 0, 0);
}

// ---------------- merged prep: cvt_x split + weight transposes + bias concat ----------------
// grid layout: [0,12288) cvt_x ; [12288,13152) transpose (12x12x6) ; [13152,13165) bias
__global__ void prep_all(
    const float* __restrict__ x, u16* __restrict__ xhi, u16* __restrict__ xlo,
    const float* __restrict__ cls_w1, const float* __restrict__ ew_w1,
    const float* __restrict__ we_w1,  const float* __restrict__ cls_w2,
    const float* __restrict__ ew_w2,  const float* __restrict__ we_w2,
    u16* BT1, u16* BTwe_hi, u16* BTwe_lo,
    u16* BT2cls, u16* BT2ew, u16* BT2we_hi, u16* BT2we_lo,
    const float* __restrict__ cls_b1, const float* __restrict__ ew_b1,
    const float* __restrict__ we_b1,  const float* __restrict__ cls_b2,
    const float* __restrict__ ew_b2,  const float* __restrict__ we_b2,
    float* b1ce, float* b1we, float* b2cls, float* b2ew, float* b2we) {
  __shared__ float t[64][65];
  const int bid = blockIdx.x;
  if (bid < 12288) {                       // ---- x -> (hi,lo) bf16 split
    int i = bid * 256 + threadIdx.x;       // 12288*256 = 16384*768/4 exact
    float4 v = ((const float4*)x)[i];
    ushort4 h, l;
    h.x = f2bf(v.x); l.x = f2bf(v.x - bf2f(h.x));
    h.y = f2bf(v.y); l.y = f2bf(v.y - bf2f(h.y));
    h.z = f2bf(v.z); l.z = f2bf(v.z - bf2f(h.z));
    h.w = f2bf(v.w); l.w = f2bf(v.w - bf2f(h.w));
    ((ushort4*)xhi)[i] = h;
    ((ushort4*)xlo)[i] = l;
    return;
  }
  if (bid < 13152) {                       // ---- LDS-tiled transpose W[768][N] -> BT[Npad][768]
    const int idx = bid - 12288;
    const int bx = idx % 12, by = (idx / 12) % 12, bz = idx / 144;
    const float* src; int N; u16* dhi; u16* dlo = nullptr;
    switch (bz) {
      case 0: src = cls_w1; N = 768; dhi = BT1; break;
      case 1: src = ew_w1;  N = 768; dhi = BT1 + 768 * 768; break;
      case 2: src = we_w1;  N = 768; dhi = BTwe_hi; dlo = BTwe_lo; break;
      case 3: src = cls_w2; N = 744; dhi = BT2cls; break;
      case 4: src = ew_w2;  N = 124; dhi = BT2ew; break;
      default: src = we_w2; N = 124; dhi = BT2we_hi; dlo = BT2we_lo; break;
    }
    const int Npad = (N + 127) & ~127;
    const int n0 = by * 64;
    if (n0 >= Npad) return;
    const int k0 = bx * 64;
    const int tx = threadIdx.x & 63, tg = threadIdx.x >> 6;
#pragma unroll
    for (int r = 0; r < 16; ++r) {
      int k = tg * 16 + r;
      int n = n0 + tx;
      t[k][tx] = (n < N) ? src[(size_t)(k0 + k) * N + n] : 0.f;   // coalesced read
    }
    __syncthreads();
#pragma unroll
    for (int r = 0; r < 16; ++r) {
      int n = n0 + tg * 16 + r;
      if (n < Npad) {
        float v = t[tx][tg * 16 + r];
        u16 h = f2bf(v);
        dhi[(size_t)n * 768 + k0 + tx] = h;                       // coalesced write
        if (dlo) dlo[(size_t)n * 768 + k0 + tx] = f2bf(v - bf2f(h));
      }
    }
    return;
  }
  // ---- bias concat/pad: 13 blocks * 256 = 3328 = 1536+768+768+128+128 exact
  int id = (bid - 13152) * 256 + threadIdx.x;
  if (id < 1536) { b1ce[id] = (id < 768) ? cls_b1[id] : ew_b1[id - 768]; return; }
  id -= 1536;
  if (id < 768) { b1we[id] = we_b1[id]; return; }
  id -= 768;
  if (id < 768) { b2cls[id] = (id < 744) ? cls_b2[id] : 0.f; return; }
  id -= 768;
  if (id < 128) { b2ew[id] = (id < 124) ? ew_b2[id] : 0.f; return; }
  id -= 128;
  if (id < 128) { b2we[id] = (id < 124) ? we_b2[id] : 0.f; return; }
}

// ---------------- GEMM core (R2-exact): 128x128 tile, BK=64, 4 waves 2x2, XOR-swizzled LDS ----------------
// LDS: logical (row, c8) at physical c8p = c8 ^ (row&7) -> conflict-free ds_read_b128 (R2: 0 conflicts).
__device__ __forceinline__ void gemm_core(
    const u16* A0, const u16* A1, const u16* A2, int lda,
    const u16* B0, const u16* B1, const u16* B2,   // pre-offset by bn*K
    int npass, int K, int bm, int tid, u16* sA, u16* sB, f32x4 acc[4][4]) {
  const int lane = tid & 63;
  const int wv = tid >> 6;
  const int wr = wv >> 1, wc = wv & 1;
  const int sr = lane >> 3;                        // staging row within 8-row group
  const int sc = (((lane & 7) ^ sr) << 3);         // swizzled source col group
  for (int p = 0; p < npass; ++p) {
    const u16* A = (p == 0) ? A0 : ((p == 1) ? A1 : A2);
    const u16* Bp = (p == 0) ? B0 : ((p == 1) ? B1 : B2);
    const u16* gA = A + (size_t)(bm + wv * 32 + sr) * lda + sc;
    const u16* gB = Bp + (size_t)(wv * 32 + sr) * K + sc;
    u16* lA = sA + (wv * 32) * 64;
    u16* lB = sB + (wv * 32) * 64;
    for (int kt = 0; kt < K; kt += 64) {
#pragma unroll
      for (int s = 0; s < 4; ++s) {
        g2l16(gA + (size_t)(s * 8) * lda + kt, lA + s * 8 * 64);
        g2l16(gB + (size_t)(s * 8) * K + kt, lB + s * 8 * 64);
      }
      __syncthreads();
#pragma unroll
      for (int ks = 0; ks < 2; ++ks) {
        const int co = ((ks * 4 + (lane >> 4)) ^ (lane & 7)) * 8;  // row&7 == lane&7 for all frags
        short8 av[4], bv[4];
#pragma unroll
        for (int i = 0; i < 4; i++)
          av[i] = *(const short8*)(sA + (wr * 64 + i * 16 + (lane & 15)) * 64 + co);
#pragma unroll
        for (int j = 0; j < 4; j++)
          bv[j] = *(const short8*)(sB + (wc * 64 + j * 16 + (lane & 15)) * 64 + co);
#pragma unroll
        for (int i = 0; i < 4; i++)
#pragma unroll
          for (int j = 0; j < 4; j++)
            acc[i][j] = __builtin_amdgcn_mfma_f32_16x16x32_bf16(av[i], bv[j], acc[i][j], 0, 0, 0);
      }
      __syncthreads();
    }
  }
}

// XCD/L2 swizzle for 128-row tiles: xcd=bid&7 owns 16 row-chunks; 8-row sub-bands, rows fastest.
__device__ __forceinline__ void decode_bid(int bid, int NC, int& bm, int& bn) {
  const int xcd = bid & 7, slot = bid >> 3;
  const int per = NC << 3;
  const int sub = slot / per, rem = slot - sub * per;
  const int colu = rem >> 3, rowIn = rem & 7;
  bm = ((xcd << 4) + (sub << 3) + rowIn) << 7;
  bn = colu << 7;
}

// MODE 0: gelu -> bf16. R2-exact config (256 thr, 32KB LDS): the only config observed at full clock.
// R3/R4 lesson: NW=4 dense variant trips the power limit and throttles EVERY later dispatch ~35%.
template <int MODE>
__global__ __launch_bounds__(256, 4) void gemm_k(
    const u16* A0, const u16* A1, const u16* A2, int lda,
    const u16* B0, const u16* B1, const u16* B2,
    int npass, int K, const float* __restrict__ bias,
    void* out0, void* out1, int ldc, int NC) {
  __shared__ u16 sA[128 * 64];
  __shared__ u16 sB[128 * 64];
  const int tid = threadIdx.x;
  const int lane = tid & 63;
  const int wr = (tid >> 6) >> 1, wc = (tid >> 6) & 1;
  int bm, bn;
  decode_bid(blockIdx.x, NC, bm, bn);

  f32x4 acc[4][4];
#pragma unroll
  for (int i = 0; i < 4; i++)
#pragma unroll
    for (int j = 0; j < 4; j++) acc[i][j] = f32x4{0.f, 0.f, 0.f, 0.f};

  const size_t bo = (size_t)bn * K;
  gemm_core(A0, A1, A2, lda, B0 + bo, B1 ? B1 + bo : nullptr, B2 ? B2 + bo : nullptr,
            npass, K, bm, tid, sA, sB, acc);

  // C/D layout: col=lane&15, row=(lane>>4)*4+r  [verified m89/m91]
#pragma unroll
  for (int j = 0; j < 4; j++) {
    const int col = bn + wc * 64 + j * 16 + (lane & 15);
    const float bs = bias[col];
#pragma unroll
    for (int i = 0; i < 4; i++) {
      const int row0 = bm + wr * 64 + i * 16 + (lane >> 4) * 4;
#pragma unroll
      for (int r = 0; r < 4; r++) {
        float v = acc[i][j][r] + bs;
        const size_t idx = (size_t)(row0 + r) * ldc + col;
        float g = 0.5f * v * (1.0f + erff(v * 0.70710678118654752f));  // exact GELU
        u16 h = f2bf(g);
        ((u16*)out0)[idx] = h;
        if (MODE == 2) ((u16*)out1)[idx] = f2bf(g - bf2f(h));
      }
    }
  }
}

// ---------------- fused 3-term split GEMM for which_expert fc1 ----------------
// C = Ahi*Bhi^T + Alo*Bhi^T + Ahi*Blo^T in ONE K-loop. LDS rows pack [hi(32)|lo(32)]
// = 128B/row, so the proven XOR-8 granule swizzle applies unchanged. The hi/lo source
// select is per-lane on the global_load_lds address. 24 K-tiles vs 36 pass-tiles:
// staging traffic x2/3, barriers x2/3, 48 MFMA per wave per barrier-pair.
__global__ __launch_bounds__(256, 3) void gemm_we(
    const u16* __restrict__ Ahi, const u16* __restrict__ Alo, int lda,
    const u16* __restrict__ Bhi, const u16* __restrict__ Blo,   // [N][K] rows, ldb=K
    int K, const float* __restrict__ bias,
    u16* __restrict__ out_hi, u16* __restrict__ out_lo, int ldc, int NC) {
  __shared__ u16 sA[128 * 64];   // 128 rows x ([hi32|lo32]) , granule-swizzled
  __shared__ u16 sB[128 * 64];
  const int tid = threadIdx.x;
  const int lane = tid & 63;
  const int wv = tid >> 6;
  const int wr = wv >> 1, wc = wv & 1;
  int bm, bn;
  decode_bid(blockIdx.x, NC, bm, bn);

  const int sr = lane >> 3;                  // row within 8-row staging group
  const int gl = (lane & 7) ^ sr;            // logical granule stored at this lane's phys slot
  const int koff = (gl & 3) << 3;            // element offset within the 32-elem half
  const u16* Asel = (gl < 4) ? Ahi : Alo;
  const u16* Bsel = (gl < 4) ? Bhi : Blo;
  const u16* gA = Asel + (size_t)(bm + wv * 32 + sr) * lda + koff;
  const u16* gB = Bsel + (size_t)(bn + wv * 32 + sr) * (size_t)K + koff;
  u16* lA = sA + (wv * 32) * 64;
  u16* lB = sB + (wv * 32) * 64;

  f32x4 acc[4][4];
#pragma unroll
  for (int i = 0; i < 4; i++)
#pragma unroll
    for (int j = 0; j < 4; j++) acc[i][j] = f32x4{0.f, 0.f, 0.f, 0.f};

  for (int kt = 0; kt < K; kt += 32) {
#pragma unroll
    for (int s = 0; s < 4; ++s) {
      g2l16(gA + (size_t)(s * 8) * lda + kt, lA + s * 8 * 64);
      g2l16(gB + (size_t)(s * 8) * K + kt, lB + s * 8 * 64);
    }
    __syncthreads();
    // fragment granule: hi at (kg ^ row&7), lo at same ^ 4 -> element offset ^32.
    const int coh = (((lane >> 4) ^ (lane & 7)) << 3);
    short8 ah[4], al[4], bh[4], bl[4];
#pragma unroll
    for (int i = 0; i < 4; i++) {
      const u16* p = sA + (wr * 64 + i * 16 + (lane & 15)) * 64;
      ah[i] = *(const short8*)(p + coh);
      al[i] = *(const short8*)(p + (coh ^ 32));
    }
#pragma unroll
    for (int j = 0; j < 4; j++) {
      const u16* p = sB + (wc * 64 + j * 16 + (lane & 15)) * 64;
      bh[j] = *(const short8*)(p + coh);
      bl[j] = *(const short8*)(p + (coh ^ 32));
    }
#pragma unroll
    for (int i = 0; i < 4; i++)
#pragma unroll
      for (int j = 0; j < 4; j++) {
        acc[i][j] = __builtin_amdgcn_mfma_f32_16x16x32_bf16(ah[i], bh[j], acc[i][j], 0, 0, 0);
        acc[i][j] = __builtin_amdgcn_mfma_f32_16x16x32_bf16(al[i], bh[j], acc[i][j], 0, 0, 0);
        acc[i][j] = __builtin_amdgcn_mfma_f32_16x16x32_bf16(ah[i], bl[j], acc[i][j], 0, 0, 0);
      }
    __syncthreads();
  }
  // epilogue: gelu -> bf16 hi + lo
#pragma unroll
  for (int j = 0; j < 4; j++) {
    const int col = bn + wc * 64 + j * 16 + (lane & 15);
    const float bs = bias[col];
#pragma unroll
    for (int i = 0; i < 4; i++) {
      const int row0 = bm + wr * 64 + i * 16 + (lane >> 4) * 4;
#pragma unroll
      for (int r = 0; r < 4; r++) {
        float v = acc[i][j][r] + bs;
        const size_t idx = (size_t)(row0 + r) * ldc + col;
        float g = 0.5f * v * (1.0f + erff(v * 0.70710678118654752f));
        u16 h = f2bf(g);
        out_hi[idx] = h;
        out_lo[idx] = f2bf(g - bf2f(h));
      }
    }
  }
}

// fused fc2, heavy-first bid order (all 1024 blocks co-resident at 4/CU):
//   bid [0,128) -> we 3-pass split ; [128,256) -> ew ; [256,1024) -> cls
__global__ __launch_bounds__(256, 4) void gemm2_fused(
    const u16* __restrict__ h_cls,                  // [16384][1536]: cls cols 0..767, ew cols 768..1535
    const u16* __restrict__ hwe_hi, const u16* __restrict__ hwe_lo,
    const u16* __restrict__ BT2cls, const u16* __restrict__ BT2ew,
    const u16* __restrict__ BT2we_hi, const u16* __restrict__ BT2we_lo,
    const float* __restrict__ b2cls, const float* __restrict__ b2ew,
    const float* __restrict__ b2we,
    u16* __restrict__ Lcls, float* __restrict__ Lew, float* __restrict__ Lwe) {
  __shared__ u16 sA[128 * 64];
  __shared__ u16 sB[128 * 64];
  const int tid = threadIdx.x;
  const int lane = tid & 63;
  const int wr = (tid >> 6) >> 1, wc = (tid >> 6) & 1;

  f32x4 acc[4][4];
#pragma unroll
  for (int i = 0; i < 4; i++)
#pragma unroll
    for (int j = 0; j < 4; j++) acc[i][j] = f32x4{0.f, 0.f, 0.f, 0.f};

  const int bid = blockIdx.x;
  if (bid >= 256) {                        // ---- cls: 768 blocks, 6 col-tiles
    int bm, bn;
    decode_bid(bid - 256, 6, bm, bn);
    gemm_core(h_cls, nullptr, nullptr, 1536, BT2cls + (size_t)bn * 768, nullptr, nullptr,
              1, 768, bm, tid, sA, sB, acc);
#pragma unroll
    for (int j = 0; j < 4; j++) {
      const int col = bn + wc * 64 + j * 16 + (lane & 15);
      const float bs = b2cls[col];
#pragma unroll
      for (int i = 0; i < 4; i++) {
        const int row0 = bm + wr * 64 + i * 16 + (lane >> 4) * 4;
#pragma unroll
        for (int r = 0; r < 4; r++)
          Lcls[(size_t)(row0 + r) * 768 + col] = f2bf(acc[i][j][r] + bs);
      }
    }
  } else {                                 // ---- heavy: we [0,128), ew [128,256)
    const bool is_we = (bid < 128);
    const int r = is_we ? bid : bid - 128;
    const int bm = (((r & 7) << 4) + (r >> 3)) << 7;   // xcd owns 16 row-chunks
    if (is_we)
      gemm_core(hwe_hi, hwe_lo, hwe_hi, 768, BT2we_hi, BT2we_hi, BT2we_lo,
                3, 768, bm, tid, sA, sB, acc);
    else
      gemm_core(h_cls + 768, nullptr, nullptr, 1536, BT2ew, nullptr, nullptr,
                1, 768, bm, tid, sA, sB, acc);
    float* o = is_we ? Lwe : Lew;
    const float* bp = is_we ? b2we : b2ew;
#pragma unroll
    for (int j = 0; j < 4; j++) {
      const int col = wc * 64 + j * 16 + (lane & 15);
      const float bs = bp[col];
#pragma unroll
      for (int i = 0; i < 4; i++) {
        const int row0 = bm + wr * 64 + i * 16 + (lane >> 4) * 4;
#pragma unroll
        for (int r2 = 0; r2 < 4; r2++)
          o[(size_t)(row0 + r2) * 128 + col] = acc[i][j][r2] + bs;
      }
    }
  }
}

// ---------------- finalize: rank-select mask (== reference threshold), softmaxes, mixture ----------------
// keep_i  <=>  which_i >= n-th largest  <=>  #{j : w_j > w_i} < n   (ties keep both, same as ref)
__global__ __launch_bounds__(256) void finalize(
    const u16* __restrict__ Lcls,   // bf16 [B][768], expert e at cols e*6..e*6+5
    const float* __restrict__ Lwe,  // f32 [B][128]
    const float* __restrict__ Lew,  // f32 [B][128]
    const int* __restrict__ nexp, float* __restrict__ out) {
  const int bid = blockIdx.x;
  const int g = ((bid & 7) << 9) + (bid >> 3);      // XCD band matches gemm2's row mapping
  const int b = (g << 2) + (int)(threadIdx.x >> 6); // 4 rows/block, one wave each
  const int lane = threadIdx.x & 63;
  const float NEG = -3.0e38f;
  const float w0 = (lane < 124) ? Lwe[(size_t)b * 128 + lane] : NEG;
  const float w1 = (lane < 60) ? Lwe[(size_t)b * 128 + 64 + lane] : NEG;
  int r0 = 0, r1 = 0;
#pragma unroll
  for (int j = 0; j < 64; ++j) {
    float v = __shfl(w0, j, 64);
    r0 += (v > w0); r1 += (v > w1);
  }
#pragma unroll
  for (int j = 0; j < 64; ++j) {
    float v = __shfl(w1, j, 64);
    r0 += (v > w0); r1 += (v > w1);
  }
  int n = nexp[b];
  n = n < 1 ? 1 : (n > 124 ? 124 : n);
  const bool k0 = (lane < 124) && (r0 < n);
  const bool k1 = (lane < 60) && (r1 < n);
  float l0 = k0 ? Lew[(size_t)b * 128 + lane] : NEG;
  float l1 = k1 ? Lew[(size_t)b * 128 + 64 + lane] : NEG;
  float mx = fmaxf(l0, l1);
#pragma unroll
  for (int o = 32; o > 0; o >>= 1) mx = fmaxf(mx, __shfl_xor(mx, o, 64));
  float e0 = k0 ? __expf(l0 - mx) : 0.f;
  float e1 = k1 ? __expf(l1 - mx) : 0.f;
  float S = e0 + e1;
#pragma unroll
  for (int o = 32; o > 0; o >>= 1) S += __shfl_xor(S, o, 64);
  float a0 = 0, a1 = 0, a2 = 0, a3 = 0, a4 = 0, a5 = 0;
#pragma unroll
  for (int h = 0; h < 2; ++h) {
    int e = lane + h * 64;
    float we = h ? e1 : e0;
    if (we > 0.f) {
      const u16* lp = Lcls + (size_t)b * 768 + e * 6;
      float c0 = bf2f(lp[0]), c1 = bf2f(lp[1]), c2 = bf2f(lp[2]);
      float c3 = bf2f(lp[3]), c4 = bf2f(lp[4]), c5 = bf2f(lp[5]);
      float m = fmaxf(fmaxf(fmaxf(c0, c1), fmaxf(c2, c3)), fmaxf(c4, c5));
      float p0 = __expf(c0 - m), p1 = __expf(c1 - m), p2 = __expf(c2 - m);
      float p3 = __expf(c3 - m), p4 = __expf(c4 - m), p5 = __expf(c5 - m);
      float inv = we / (p0 + p1 + p2 + p3 + p4 + p5);
      a0 += p0 * inv; a1 += p1 * inv; a2 += p2 * inv;
      a3 += p3 * inv; a4 += p4 * inv; a5 += p5 * inv;
    }
  }
#pragma unroll
  for (int o = 32; o > 0; o >>= 1) {
    a0 += __shfl_xor(a0, o, 64); a1 += __shfl_xor(a1, o, 64);
    a2 += __shfl_xor(a2, o, 64); a3 += __shfl_xor(a3, o, 64);
    a4 += __shfl_xor(a4, o, 64); a5 += __shfl_xor(a5, o, 64);
  }
  if (lane < 6) {
    float v = (lane == 0) ? a0 : (lane == 1) ? a1 : (lane == 2) ? a2
              : (lane == 3) ? a3 : (lane == 4) ? a4 : a5;
    out[(size_t)b * 6 + lane] = v / S;
  }
}

__global__ void fill_sentinel(float* out, int n, float v) {
  int i = blockIdx.x * 256 + threadIdx.x;
  if (i < n) out[i] = v;
}

extern "C" void kernel_launch(void* const* d_in, const int* in_sizes, int n_in,
                              void* d_out, int out_size, void* d_ws, size_t ws_size,
                              hipStream_t stream) {
  const float* x = (const float*)d_in[0];
  const int* nexp = (const int*)d_in[1];
  const float* cls_w1 = (const float*)d_in[2];
  const float* cls_b1 = (const float*)d_in[3];
  const float* cls_w2 = (const float*)d_in[4];
  const float* cls_b2 = (const float*)d_in[5];
  const float* we_w1 = (const float*)d_in[6];
  const float* we_b1 = (const float*)d_in[7];
  const float* we_w2 = (const float*)d_in[8];
  const float* we_b2 = (const float*)d_in[9];
  const float* ew_w1 = (const float*)d_in[10];
  const float* ew_b1 = (const float*)d_in[11];
  const float* ew_w2 = (const float*)d_in[12];
  const float* ew_b2 = (const float*)d_in[13];
  float* out = (float*)d_out;
  char* ws = (char*)d_ws;

  if (ws_size < WS_NEED) {  // diagnosable failure: absmax ~12345
    fill_sentinel<<<(out_size + 255) / 256, 256, 0, stream>>>(out, out_size, 12345.0f);
    return;
  }

  u16* xhi = (u16*)(ws + OFF_XHI);
  u16* xlo = (u16*)(ws + OFF_XLO);
  u16* Lcls = (u16*)(ws + OFF_LCLS);
  float* Lwe = (float*)(ws + OFF_LWE);
  float* Lew = (float*)(ws + OFF_LEW);
  u16* BT1 = (u16*)(ws + OFF_BT1);
  u16* BTwe_hi = (u16*)(ws + OFF_BTWE_HI);
  u16* BTwe_lo = (u16*)(ws + OFF_BTWE_LO);
  u16* BT2cls = (u16*)(ws + OFF_BT2CLS);
  u16* BT2ew = (u16*)(ws + OFF_BT2EW);
  u16* BT2we_hi = (u16*)(ws + OFF_BT2WE_HI);
  u16* BT2we_lo = (u16*)(ws + OFF_BT2WE_LO);
  float* b1ce = (float*)(ws + OFF_B1CE);
  float* b1we = (float*)(ws + OFF_B1WE);
  float* b2cls = (float*)(ws + OFF_B2CLS);
  float* b2ew = (float*)(ws + OFF_B2EW);
  float* b2we = (float*)(ws + OFF_B2WE);
  u16* h_clsew = (u16*)(ws + OFF_HCLSEW);
  u16* h_we_hi = (u16*)(ws + OFF_HWE_HI);
  u16* h_we_lo = (u16*)(ws + OFF_HWE_LO);

  prep_all<<<13165, 256, 0, stream>>>(x, xhi, xlo,
                                      cls_w1, ew_w1, we_w1, cls_w2, ew_w2, we_w2,
                                      BT1, BTwe_hi, BTwe_lo, BT2cls, BT2ew, BT2we_hi, BT2we_lo,
                                      cls_b1, ew_b1, we_b1, cls_b2, ew_b2, we_b2,
                                      b1ce, b1we, b2cls, b2ew, b2we);
  // fc1 cls+ew (N=1536): R2-exact NW=2 config (full-clock reference point)
  gemm_k<0><<<1536, 256, 0, stream>>>(xhi, nullptr, nullptr, 768,
                                      BT1, nullptr, nullptr, 1, 768,
                                      b1ce, h_clsew, nullptr, 1536, 12);
  // fc1 we: fused 3-term split in one K-loop (24 K-tiles, 48 MFMA/wave/tile)
  gemm_we<<<768, 256, 0, stream>>>(xhi, xlo, 768, BTwe_hi, BTwe_lo, 768,
                                   b1we, h_we_hi, h_we_lo, 768, 6);
  // fc2 all three heads in one dispatch, heavy (3-pass we) blocks first
  gemm2_fused<<<1024, 256, 0, stream>>>(h_clsew, h_we_hi, h_we_lo,
                                        BT2cls, BT2ew, BT2we_hi, BT2we_lo,
                                        b2cls, b2ew, b2we, Lcls, Lew, Lwe);
  finalize<<<4096, 256, 0, stream>>>(Lcls, Lwe, Lew, nexp, out);
}

// Round 6
// 369.186 us; speedup vs baseline: 1.1593x; 1.0260x over previous
//
#include <hip/hip_runtime.h>
#include <stdint.h>

typedef unsigned short u16;
typedef short short8 __attribute__((ext_vector_type(8)));
typedef float f32x4 __attribute__((ext_vector_type(4)));

// Problem sizes: B=16384, D=768, E=124 (pad 128), C=6, E*C=744 (pad 768)
#define NB 16384

// ---- workspace layout (bytes) ----
#define OFF_XHI      0ull            // bf16 [16384][768]
#define OFF_XLO      25165824ull     // bf16 [16384][768]
#define OFF_LCLS     0ull            // aliases XHI: bf16 [16384][768] class logits (cols 0..743 real)
#define OFF_LWE      25165824ull     // aliases XLO: f32 [16384][128] which_expert
#define OFF_LEW      33554432ull     // f32 [16384][128] expert-weight logits
#define OFF_BT1      50331648ull     // bf16 [1536][768]  (cls_w1^T ; ew_w1^T)
#define OFF_BTWE_HI  52690944ull     // bf16 [768][768]
#define OFF_BTWE_LO  53870592ull
#define OFF_BT2CLS   55050240ull     // bf16 [768][768] (744 real rows, padded w/ 0)
#define OFF_BT2EW    56229888ull     // bf16 [128][768]
#define OFF_BT2WE_HI 56426496ull
#define OFF_BT2WE_LO 56623104ull
#define OFF_B1CE     56819712ull     // f32 [1536]
#define OFF_B1WE     56825856ull     // f32 [768]
#define OFF_B2CLS    56828928ull     // f32 [768]
#define OFF_B2EW     56832000ull     // f32 [128]
#define OFF_B2WE     56832512ull     // f32 [128]
#define OFF_HCLSEW   56833024ull     // bf16 [16384][1536] gelu(h) for cls|ew
#define OFF_HWE_HI   107164672ull    // bf16 [16384][768]
#define OFF_HWE_LO   132330496ull    // bf16 [16384][768]
#define WS_NEED      157496320ull

__device__ __forceinline__ u16 f2bf(float f) {          // RNE f32->bf16
  uint32_t u = __float_as_uint(f);
  u += 0x7fffu + ((u >> 16) & 1u);
  return (u16)(u >> 16);
}
__device__ __forceinline__ float bf2f(u16 h) {
  return __uint_as_float(((uint32_t)h) << 16);
}
__device__ __forceinline__ void g2l16(const u16* g, u16* l) {
  // async global->LDS, 16B/lane; LDS dest = wave-uniform base + lane*16 (HW rule).
  // Global side is a normal per-lane address -> per-lane source permutation is legal.
  __builtin_amdgcn_global_load_lds(
      (__attribute__((address_space(1))) void*)(u16*)g,
      (__attribute__((address_space(3))) void*)l, 16, 0, 0);
}

// ---------------- merged prep: cvt_x split + weight transposes + bias concat ----------------
// grid layout: [0,12288) cvt_x ; [12288,13152) transpose (12x12x6) ; [13152,13165) bias
__global__ void prep_all(
    const float* __restrict__ x, u16* __restrict__ xhi, u16* __restrict__ xlo,
    const float* __restrict__ cls_w1, const float* __restrict__ ew_w1,
    const float* __restrict__ we_w1,  const float* __restrict__ cls_w2,
    const float* __restrict__ ew_w2,  const float* __restrict__ we_w2,
    u16* BT1, u16* BTwe_hi, u16* BTwe_lo,
    u16* BT2cls, u16* BT2ew, u16* BT2we_hi, u16* BT2we_lo,
    const float* __restrict__ cls_b1, const float* __restrict__ ew_b1,
    const float* __restrict__ we_b1,  const float* __restrict__ cls_b2,
    const float* __restrict__ ew_b2,  const float* __restrict__ we_b2,
    float* b1ce, float* b1we, float* b2cls, float* b2ew, float* b2we) {
  __shared__ float t[64][65];
  const int bid = blockIdx.x;
  if (bid < 12288) {                       // ---- x -> (hi,lo) bf16 split
    int i = bid * 256 + threadIdx.x;       // 12288*256 = 16384*768/4 exact
    float4 v = ((const float4*)x)[i];
    ushort4 h, l;
    h.x = f2bf(v.x); l.x = f2bf(v.x - bf2f(h.x));
    h.y = f2bf(v.y); l.y = f2bf(v.y - bf2f(h.y));
    h.z = f2bf(v.z); l.z = f2bf(v.z - bf2f(h.z));
    h.w = f2bf(v.w); l.w = f2bf(v.w - bf2f(h.w));
    ((ushort4*)xhi)[i] = h;
    ((ushort4*)xlo)[i] = l;
    return;
  }
  if (bid < 13152) {                       // ---- LDS-tiled transpose W[768][N] -> BT[Npad][768]
    const int idx = bid - 12288;
    const int bx = idx % 12, by = (idx / 12) % 12, bz = idx / 144;
    const float* src; int N; u16* dhi; u16* dlo = nullptr;
    switch (bz) {
      case 0: src = cls_w1; N = 768; dhi = BT1; break;
      case 1: src = ew_w1;  N = 768; dhi = BT1 + 768 * 768; break;
      case 2: src = we_w1;  N = 768; dhi = BTwe_hi; dlo = BTwe_lo; break;
      case 3: src = cls_w2; N = 744; dhi = BT2cls; break;
      case 4: src = ew_w2;  N = 124; dhi = BT2ew; break;
      default: src = we_w2; N = 124; dhi = BT2we_hi; dlo = BT2we_lo; break;
    }
    const int Npad = (N + 127) & ~127;
    const int n0 = by * 64;
    if (n0 >= Npad) return;
    const int k0 = bx * 64;
    const int tx = threadIdx.x & 63, tg = threadIdx.x >> 6;
#pragma unroll
    for (int r = 0; r < 16; ++r) {
      int k = tg * 16 + r;
      int n = n0 + tx;
      t[k][tx] = (n < N) ? src[(size_t)(k0 + k) * N + n] : 0.f;   // coalesced read
    }
    __syncthreads();
#pragma unroll
    for (int r = 0; r < 16; ++r) {
      int n = n0 + tg * 16 + r;
      if (n < Npad) {
        float v = t[tx][tg * 16 + r];
        u16 h = f2bf(v);
        dhi[(size_t)n * 768 + k0 + tx] = h;                       // coalesced write
        if (dlo) dlo[(size_t)n * 768 + k0 + tx] = f2bf(v - bf2f(h));
      }
    }
    return;
  }
  // ---- bias concat/pad: 13 blocks * 256 = 3328 = 1536+768+768+128+128 exact
  int id = (bid - 13152) * 256 + threadIdx.x;
  if (id < 1536) { b1ce[id] = (id < 768) ? cls_b1[id] : ew_b1[id - 768]; return; }
  id -= 1536;
  if (id < 768) { b1we[id] = we_b1[id]; return; }
  id -= 768;
  if (id < 768) { b2cls[id] = (id < 744) ? cls_b2[id] : 0.f; return; }
  id -= 768;
  if (id < 128) { b2ew[id] = (id < 124) ? ew_b2[id] : 0.f; return; }
  id -= 128;
  if (id < 128) { b2we[id] = (id < 124) ? we_b2[id] : 0.f; return; }
}

// ---------------- GEMM core (R2-exact): 128x128 tile, BK=64, 4 waves 2x2, XOR-swizzled LDS ----------------
// LDS: logical (row, c8) at physical c8p = c8 ^ (row&7) -> conflict-free ds_read_b128 (R2: 0 conflicts).
__device__ __forceinline__ void gemm_core(
    const u16* A0, const u16* A1, const u16* A2, int lda,
    const u16* B0, const u16* B1, const u16* B2,   // pre-offset by bn*K
    int npass, int K, int bm, int tid, u16* sA, u16* sB, f32x4 acc[4][4]) {
  const int lane = tid & 63;
  const int wv = tid >> 6;
  const int wr = wv >> 1, wc = wv & 1;
  const int sr = lane >> 3;                        // staging row within 8-row group
  const int sc = (((lane & 7) ^ sr) << 3);         // swizzled source col group
  for (int p = 0; p < npass; ++p) {
    const u16* A = (p == 0) ? A0 : ((p == 1) ? A1 : A2);
    const u16* Bp = (p == 0) ? B0 : ((p == 1) ? B1 : B2);
    const u16* gA = A + (size_t)(bm + wv * 32 + sr) * lda + sc;
    const u16* gB = Bp + (size_t)(wv * 32 + sr) * K + sc;
    u16* lA = sA + (wv * 32) * 64;
    u16* lB = sB + (wv * 32) * 64;
    for (int kt = 0; kt < K; kt += 64) {
#pragma unroll
      for (int s = 0; s < 4; ++s) {
        g2l16(gA + (size_t)(s * 8) * lda + kt, lA + s * 8 * 64);
        g2l16(gB + (size_t)(s * 8) * K + kt, lB + s * 8 * 64);
      }
      __syncthreads();
#pragma unroll
      for (int ks = 0; ks < 2; ++ks) {
        const int co = ((ks * 4 + (lane >> 4)) ^ (lane & 7)) * 8;  // row&7 == lane&7 for all frags
        short8 av[4], bv[4];
#pragma unroll
        for (int i = 0; i < 4; i++)
          av[i] = *(const short8*)(sA + (wr * 64 + i * 16 + (lane & 15)) * 64 + co);
#pragma unroll
        for (int j = 0; j < 4; j++)
          bv[j] = *(const short8*)(sB + (wc * 64 + j * 16 + (lane & 15)) * 64 + co);
#pragma unroll
        for (int i = 0; i < 4; i++)
#pragma unroll
          for (int j = 0; j < 4; j++)
            acc[i][j] = __builtin_amdgcn_mfma_f32_16x16x32_bf16(av[i], bv[j], acc[i][j], 0, 0, 0);
      }
      __syncthreads();
    }
  }
}

// XCD/L2 swizzle for 128-row tiles: xcd=bid&7 owns 16 row-chunks; 8-row sub-bands, rows fastest.
__device__ __forceinline__ void decode_bid(int bid, int NC, int& bm, int& bn) {
  const int xcd = bid & 7, slot = bid >> 3;
  const int per = NC << 3;
  const int sub = slot / per, rem = slot - sub * per;
  const int colu = rem >> 3, rowIn = rem & 7;
  bm = ((xcd << 4) + (sub << 3) + rowIn) << 7;
  bn = colu << 7;
}

// ---------------- fused fc1: BOTH heads in one dispatch ----------------
// bid [0,768)    -> which_expert fused 3-term split GEMM (heavy ~2.4x -> first)
// bid [768,2304) -> cls+ew MODE0 GEMM (light, backfills residency gaps + tail)
// Both paths are byte-identical to their R5 standalone versions (proven correct,
// full-clock). Shared 32KB LDS. R3/R4 lesson: don't raise per-CU intensity.
__global__ __launch_bounds__(256, 4) void gemm1_fused(
    const u16* __restrict__ Ahi, const u16* __restrict__ Alo,      // xhi, xlo [16384][768]
    const u16* __restrict__ Bwe_hi, const u16* __restrict__ Bwe_lo,// we_w1^T splits [768][768]
    const u16* __restrict__ BT1,                                   // [cls_w1^T; ew_w1^T] [1536][768]
    const float* __restrict__ b1we, const float* __restrict__ b1ce,
    u16* __restrict__ out_we_hi, u16* __restrict__ out_we_lo,      // [16384][768]
    u16* __restrict__ out_ce) {                                    // [16384][1536]
  __shared__ u16 smem[2 * 128 * 64];
  u16* sA = smem;
  u16* sB = smem + 128 * 64;
  const int tid = threadIdx.x;
  const int lane = tid & 63;
  const int wv = tid >> 6;
  const int wr = wv >> 1, wc = wv & 1;
  const int K = 768;

  f32x4 acc[4][4];
#pragma unroll
  for (int i = 0; i < 4; i++)
#pragma unroll
    for (int j = 0; j < 4; j++) acc[i][j] = f32x4{0.f, 0.f, 0.f, 0.f};

  if (blockIdx.x < 768) {
    // ===== which_expert: C = Ahi*Bhi^T + Alo*Bhi^T + Ahi*Blo^T in ONE K-loop =====
    // LDS rows pack [hi(32)|lo(32)] = 128B/row -> proven XOR-8 granule swizzle unchanged;
    // hi/lo select is per-lane on the global_load_lds source address.
    int bm, bn;
    decode_bid(blockIdx.x, 6, bm, bn);
    const int sr = lane >> 3;                  // row within 8-row staging group
    const int gl = (lane & 7) ^ sr;            // logical granule at this lane's phys slot
    const int koff = (gl & 3) << 3;            // element offset within the 32-elem half
    const u16* Asel = (gl < 4) ? Ahi : Alo;
    const u16* Bsel = (gl < 4) ? Bwe_hi : Bwe_lo;
    const u16* gA = Asel + (size_t)(bm + wv * 32 + sr) * K + koff;
    const u16* gB = Bsel + (size_t)(bn + wv * 32 + sr) * (size_t)K + koff;
    u16* lA = sA + (wv * 32) * 64;
    u16* lB = sB + (wv * 32) * 64;

    for (int kt = 0; kt < K; kt += 32) {
#pragma unroll
      for (int s = 0; s < 4; ++s) {
        g2l16(gA + (size_t)(s * 8) * K + kt, lA + s * 8 * 64);
        g2l16(gB + (size_t)(s * 8) * K + kt, lB + s * 8 * 64);
      }
      __syncthreads();
      // fragment granule: hi at (kg ^ row&7), lo at same ^ 4 -> element offset ^32
      const int coh = (((lane >> 4) ^ (lane & 7)) << 3);
      short8 ah[4], al[4], bh[4], bl[4];
#pragma unroll
      for (int i = 0; i < 4; i++) {
        const u16* p = sA + (wr * 64 + i * 16 + (lane & 15)) * 64;
        ah[i] = *(const short8*)(p + coh);
        al[i] = *(const short8*)(p + (coh ^ 32));
      }
#pragma unroll
      for (int j = 0; j < 4; j++) {
        const u16* p = sB + (wc * 64 + j * 16 + (lane & 15)) * 64;
        bh[j] = *(const short8*)(p + coh);
        bl[j] = *(const short8*)(p + (coh ^ 32));
      }
#pragma unroll
      for (int i = 0; i < 4; i++)
#pragma unroll
        for (int j = 0; j < 4; j++) {
          acc[i][j] = __builtin_amdgcn_mfma_f32_16x16x32_bf16(ah[i], bh[j], acc[i][j], 0, 0, 0);
          acc[i][j] = __builtin_amdgcn_mfma_f32_16x16x32_bf16(al[i], bh[j], acc[i][j], 0, 0, 0);
          acc[i][j] = __builtin_amdgcn_mfma_f32_16x16x32_bf16(ah[i], bl[j], acc[i][j], 0, 0, 0);
        }
      __syncthreads();
    }
    // epilogue: gelu -> bf16 hi + lo
#pragma unroll
    for (int j = 0; j < 4; j++) {
      const int col = bn + wc * 64 + j * 16 + (lane & 15);
      const float bs = b1we[col];
#pragma unroll
      for (int i = 0; i < 4; i++) {
        const int row0 = bm + wr * 64 + i * 16 + (lane >> 4) * 4;
#pragma unroll
        for (int r = 0; r < 4; r++) {
          float v = acc[i][j][r] + bs;
          const size_t idx = (size_t)(row0 + r) * 768 + col;
          float g = 0.5f * v * (1.0f + erff(v * 0.70710678118654752f));
          u16 h = f2bf(g);
          out_we_hi[idx] = h;
          out_we_lo[idx] = f2bf(g - bf2f(h));
        }
      }
    }
  } else {
    // ===== cls+ew fc1 (N=1536), gelu -> bf16 =====
    int bm, bn;
    decode_bid(blockIdx.x - 768, 12, bm, bn);
    gemm_core(Ahi, nullptr, nullptr, 768, BT1 + (size_t)bn * K, nullptr, nullptr,
              1, K, bm, tid, sA, sB, acc);
#pragma unroll
    for (int j = 0; j < 4; j++) {
      const int col = bn + wc * 64 + j * 16 + (lane & 15);
      const float bs = b1ce[col];
#pragma unroll
      for (int i = 0; i < 4; i++) {
        const int row0 = bm + wr * 64 + i * 16 + (lane >> 4) * 4;
#pragma unroll
        for (int r = 0; r < 4; r++) {
          float v = acc[i][j][r] + bs;
          float g = 0.5f * v * (1.0f + erff(v * 0.70710678118654752f));  // exact GELU
          out_ce[(size_t)(row0 + r) * 1536 + col] = f2bf(g);
        }
      }
    }
  }
}

// fused fc2, heavy-first bid order (all 1024 blocks co-resident at 4/CU):
//   bid [0,128) -> we 3-pass split ; [128,256) -> ew ; [256,1024) -> cls
__global__ __launch_bounds__(256, 4) void gemm2_fused(
    const u16* __restrict__ h_cls,                  // [16384][1536]: cls cols 0..767, ew cols 768..1535
    const u16* __restrict__ hwe_hi, const u16* __restrict__ hwe_lo,
    const u16* __restrict__ BT2cls, const u16* __restrict__ BT2ew,
    const u16* __restrict__ BT2we_hi, const u16* __restrict__ BT2we_lo,
    const float* __restrict__ b2cls, const float* __restrict__ b2ew,
    const float* __restrict__ b2we,
    u16* __restrict__ Lcls, float* __restrict__ Lew, float* __restrict__ Lwe) {
  __shared__ u16 sA[128 * 64];
  __shared__ u16 sB[128 * 64];
  const int tid = threadIdx.x;
  const int lane = tid & 63;
  const int wr = (tid >> 6) >> 1, wc = (tid >> 6) & 1;

  f32x4 acc[4][4];
#pragma unroll
  for (int i = 0; i < 4; i++)
#pragma unroll
    for (int j = 0; j < 4; j++) acc[i][j] = f32x4{0.f, 0.f, 0.f, 0.f};

  const int bid = blockIdx.x;
  if (bid >= 256) {                        // ---- cls: 768 blocks, 6 col-tiles
    int bm, bn;
    decode_bid(bid - 256, 6, bm, bn);
    gemm_core(h_cls, nullptr, nullptr, 1536, BT2cls + (size_t)bn * 768, nullptr, nullptr,
              1, 768, bm, tid, sA, sB, acc);
#pragma unroll
    for (int j = 0; j < 4; j++) {
      const int col = bn + wc * 64 + j * 16 + (lane & 15);
      const float bs = b2cls[col];
#pragma unroll
      for (int i = 0; i < 4; i++) {
        const int row0 = bm + wr * 64 + i * 16 + (lane >> 4) * 4;
#pragma unroll
        for (int r = 0; r < 4; r++)
          Lcls[(size_t)(row0 + r) * 768 + col] = f2bf(acc[i][j][r] + bs);
      }
    }
  } else {                                 // ---- heavy: we [0,128), ew [128,256)
    const bool is_we = (bid < 128);
    const int r = is_we ? bid : bid - 128;
    const int bm = (((r & 7) << 4) + (r >> 3)) << 7;   // xcd owns 16 row-chunks
    if (is_we)
      gemm_core(hwe_hi, hwe_lo, hwe_hi, 768, BT2we_hi, BT2we_hi, BT2we_lo,
                3, 768, bm, tid, sA, sB, acc);
    else
      gemm_core(h_cls + 768, nullptr, nullptr, 1536, BT2ew, nullptr, nullptr,
                1, 768, bm, tid, sA, sB, acc);
    float* o = is_we ? Lwe : Lew;
    const float* bp = is_we ? b2we : b2ew;
#pragma unroll
    for (int j = 0; j < 4; j++) {
      const int col = wc * 64 + j * 16 + (lane & 15);
      const float bs = bp[col];
#pragma unroll
      for (int i = 0; i < 4; i++) {
        const int row0 = bm + wr * 64 + i * 16 + (lane >> 4) * 4;
#pragma unroll
        for (int r2 = 0; r2 < 4; r2++)
          o[(size_t)(row0 + r2) * 128 + col] = acc[i][j][r2] + bs;
      }
    }
  }
}

// ---------------- finalize: rank-select mask (== reference threshold), softmaxes, mixture ----------------
// keep_i  <=>  which_i >= n-th largest  <=>  #{j : w_j > w_i} < n   (ties keep both, same as ref)
__global__ __launch_bounds__(256) void finalize(
    const u16* __restrict__ Lcls,   // bf16 [B][768], expert e at cols e*6..e*6+5
    const float* __restrict__ Lwe,  // f32 [B][128]
    const float* __restrict__ Lew,  // f32 [B][128]
    const int* __restrict__ nexp, float* __restrict__ out) {
  const int bid = blockIdx.x;
  const int g = ((bid & 7) << 9) + (bid >> 3);      // XCD band matches gemm2's row mapping
  const int b = (g << 2) + (int)(threadIdx.x >> 6); // 4 rows/block, one wave each
  const int lane = threadIdx.x & 63;
  const float NEG = -3.0e38f;
  const float w0 = (lane < 124) ? Lwe[(size_t)b * 128 + lane] : NEG;
  const float w1 = (lane < 60) ? Lwe[(size_t)b * 128 + 64 + lane] : NEG;
  int r0 = 0, r1 = 0;
#pragma unroll
  for (int j = 0; j < 64; ++j) {
    float v = __shfl(w0, j, 64);
    r0 += (v > w0); r1 += (v > w1);
  }
#pragma unroll
  for (int j = 0; j < 64; ++j) {
    float v = __shfl(w1, j, 64);
    r0 += (v > w0); r1 += (v > w1);
  }
  int n = nexp[b];
  n = n < 1 ? 1 : (n > 124 ? 124 : n);
  const bool k0 = (lane < 124) && (r0 < n);
  const bool k1 = (lane < 60) && (r1 < n);
  float l0 = k0 ? Lew[(size_t)b * 128 + lane] : NEG;
  float l1 = k1 ? Lew[(size_t)b * 128 + 64 + lane] : NEG;
  float mx = fmaxf(l0, l1);
#pragma unroll
  for (int o = 32; o > 0; o >>= 1) mx = fmaxf(mx, __shfl_xor(mx, o, 64));
  float e0 = k0 ? __expf(l0 - mx) : 0.f;
  float e1 = k1 ? __expf(l1 - mx) : 0.f;
  float S = e0 + e1;
#pragma unroll
  for (int o = 32; o > 0; o >>= 1) S += __shfl_xor(S, o, 64);
  float a0 = 0, a1 = 0, a2 = 0, a3 = 0, a4 = 0, a5 = 0;
#pragma unroll
  for (int h = 0; h < 2; ++h) {
    int e = lane + h * 64;
    float we = h ? e1 : e0;
    if (we > 0.f) {
      const u16* lp = Lcls + (size_t)b * 768 + e * 6;
      float c0 = bf2f(lp[0]), c1 = bf2f(lp[1]), c2 = bf2f(lp[2]);
      float c3 = bf2f(lp[3]), c4 = bf2f(lp[4]), c5 = bf2f(lp[5]);
      float m = fmaxf(fmaxf(fmaxf(c0, c1), fmaxf(c2, c3)), fmaxf(c4, c5));
      float p0 = __expf(c0 - m), p1 = __expf(c1 - m), p2 = __expf(c2 - m);
      float p3 = __expf(c3 - m), p4 = __expf(c4 - m), p5 = __expf(c5 - m);
      float inv = we / (p0 + p1 + p2 + p3 + p4 + p5);
      a0 += p0 * inv; a1 += p1 * inv; a2 += p2 * inv;
      a3 += p3 * inv; a4 += p4 * inv; a5 += p5 * inv;
    }
  }
#pragma unroll
  for (int o = 32; o > 0; o >>= 1) {
    a0 += __shfl_xor(a0, o, 64); a1 += __shfl_xor(a1, o, 64);
    a2 += __shfl_xor(a2, o, 64); a3 += __shfl_xor(a3, o, 64);
    a4 += __shfl_xor(a4, o, 64); a5 += __shfl_xor(a5, o, 64);
  }
  if (lane < 6) {
    float v = (lane == 0) ? a0 : (lane == 1) ? a1 : (lane == 2) ? a2
              : (lane == 3) ? a3 : (lane == 4) ? a4 : a5;
    out[(size_t)b * 6 + lane] = v / S;
  }
}

__global__ void fill_sentinel(float* out, int n, float v) {
  int i = blockIdx.x * 256 + threadIdx.x;
  if (i < n) out[i] = v;
}

extern "C" void kernel_launch(void* const* d_in, const int* in_sizes, int n_in,
                              void* d_out, int out_size, void* d_ws, size_t ws_size,
                              hipStream_t stream) {
  const float* x = (const float*)d_in[0];
  const int* nexp = (const int*)d_in[1];
  const float* cls_w1 = (const float*)d_in[2];
  const float* cls_b1 = (const float*)d_in[3];
  const float* cls_w2 = (const float*)d_in[4];
  const float* cls_b2 = (const float*)d_in[5];
  const float* we_w1 = (const float*)d_in[6];
  const float* we_b1 = (const float*)d_in[7];
  const float* we_w2 = (const float*)d_in[8];
  const float* we_b2 = (const float*)d_in[9];
  const float* ew_w1 = (const float*)d_in[10];
  const float* ew_b1 = (const float*)d_in[11];
  const float* ew_w2 = (const float*)d_in[12];
  const float* ew_b2 = (const float*)d_in[13];
  float* out = (float*)d_out;
  char* ws = (char*)d_ws;

  if (ws_size < WS_NEED) {  // diagnosable failure: absmax ~12345
    fill_sentinel<<<(out_size + 255) / 256, 256, 0, stream>>>(out, out_size, 12345.0f);
    return;
  }

  u16* xhi = (u16*)(ws + OFF_XHI);
  u16* xlo = (u16*)(ws + OFF_XLO);
  u16* Lcls = (u16*)(ws + OFF_LCLS);
  float* Lwe = (float*)(ws + OFF_LWE);
  float* Lew = (float*)(ws + OFF_LEW);
  u16* BT1 = (u16*)(ws + OFF_BT1);
  u16* BTwe_hi = (u16*)(ws + OFF_BTWE_HI);
  u16* BTwe_lo = (u16*)(ws + OFF_BTWE_LO);
  u16* BT2cls = (u16*)(ws + OFF_BT2CLS);
  u16* BT2ew = (u16*)(ws + OFF_BT2EW);
  u16* BT2we_hi = (u16*)(ws + OFF_BT2WE_HI);
  u16* BT2we_lo = (u16*)(ws + OFF_BT2WE_LO);
  float* b1ce = (float*)(ws + OFF_B1CE);
  float* b1we = (float*)(ws + OFF_B1WE);
  float* b2cls = (float*)(ws + OFF_B2CLS);
  float* b2ew = (float*)(ws + OFF_B2EW);
  float* b2we = (float*)(ws + OFF_B2WE);
  u16* h_clsew = (u16*)(ws + OFF_HCLSEW);
  u16* h_we_hi = (u16*)(ws + OFF_HWE_HI);
  u16* h_we_lo = (u16*)(ws + OFF_HWE_LO);

  prep_all<<<13165, 256, 0, stream>>>(x, xhi, xlo,
                                      cls_w1, ew_w1, we_w1, cls_w2, ew_w2, we_w2,
                                      BT1, BTwe_hi, BTwe_lo, BT2cls, BT2ew, BT2we_hi, BT2we_lo,
                                      cls_b1, ew_b1, we_b1, cls_b2, ew_b2, we_b2,
                                      b1ce, b1we, b2cls, b2ew, b2we);
  // fc1 BOTH heads in one dispatch: heavy fused-split we blocks first, cls/ew backfills
  gemm1_fused<<<2304, 256, 0, stream>>>(xhi, xlo, BTwe_hi, BTwe_lo, BT1,
                                        b1we, b1ce, h_we_hi, h_we_lo, h_clsew);
  // fc2 all three heads in one dispatch, heavy (3-pass we) blocks first
  gemm2_fused<<<1024, 256, 0, stream>>>(h_clsew, h_we_hi, h_we_lo,
                                        BT2cls, BT2ew, BT2we_hi, BT2we_lo,
                                        b2cls, b2ew, b2we, Lcls, Lew, Lwe);
  finalize<<<4096, 256, 0, stream>>>(Lcls, Lwe, Lew, nexp, out);
}

// Round 7
// 346.214 us; speedup vs baseline: 1.2362x; 1.0663x over previous
//
#include <hip/hip_runtime.h>
#include <stdint.h>

typedef unsigned short u16;
typedef short short8 __attribute__((ext_vector_type(8)));
typedef float f32x4 __attribute__((ext_vector_type(4)));

// Problem sizes: B=16384, D=768, E=124 (pad 128), C=6, E*C=744 (pad 768)
#define NB 16384

// ---- workspace layout (bytes) ----
#define OFF_XHI      0ull            // bf16 [16384][768]
#define OFF_XLO      25165824ull     // bf16 [16384][768]
#define OFF_LCLS     0ull            // aliases XHI: bf16 [16384][768] class logits (cols 0..743 real)
#define OFF_LWE      25165824ull     // aliases XLO: f32 [16384][128] which_expert
#define OFF_LEW      33554432ull     // f32 [16384][128] expert-weight logits
#define OFF_BT1      50331648ull     // bf16 [1536][768]  (cls_w1^T ; ew_w1^T)
#define OFF_BTWE_HI  52690944ull     // bf16 [768][768]
#define OFF_BTWE_LO  53870592ull
#define OFF_BT2CLS   55050240ull     // bf16 [768][768] (744 real rows, padded w/ 0)
#define OFF_BT2EW    56229888ull     // bf16 [128][768]
#define OFF_BT2WE_HI 56426496ull
#define OFF_BT2WE_LO 56623104ull
#define OFF_B1CE     56819712ull     // f32 [1536]
#define OFF_B1WE     56825856ull     // f32 [768]
#define OFF_B2CLS    56828928ull     // f32 [768]
#define OFF_B2EW     56832000ull     // f32 [128]
#define OFF_B2WE     56832512ull     // f32 [128]
#define OFF_HCLSEW   56833024ull     // bf16 [16384][1536] gelu(h) for cls|ew
#define OFF_HWE_HI   107164672ull    // bf16 [16384][768]
#define OFF_HWE_LO   132330496ull    // bf16 [16384][768]
#define WS_NEED      157496320ull

__device__ __forceinline__ u16 f2bf(float f) {          // RNE f32->bf16
  uint32_t u = __float_as_uint(f);
  u += 0x7fffu + ((u >> 16) & 1u);
  return (u16)(u >> 16);
}
__device__ __forceinline__ float bf2f(u16 h) {
  return __uint_as_float(((uint32_t)h) << 16);
}
__device__ __forceinline__ void g2l16(const u16* g, u16* l) {
  // async global->LDS, 16B/lane; LDS dest = wave-uniform base + lane*16 (HW rule).
  // Global side is a normal per-lane address -> per-lane source permutation is legal.
  __builtin_amdgcn_global_load_lds(
      (__attribute__((address_space(1))) void*)(u16*)g,
      (__attribute__((address_space(3))) void*)l, 16, 0, 0);
}

// ---------------- merged prep: cvt_x split + weight transposes + bias concat ----------------
// grid layout: [0,12288) cvt_x ; [12288,13152) transpose (12x12x6) ; [13152,13165) bias
__global__ void prep_all(
    const float* __restrict__ x, u16* __restrict__ xhi, u16* __restrict__ xlo,
    const float* __restrict__ cls_w1, const float* __restrict__ ew_w1,
    const float* __restrict__ we_w1,  const float* __restrict__ cls_w2,
    const float* __restrict__ ew_w2,  const float* __restrict__ we_w2,
    u16* BT1, u16* BTwe_hi, u16* BTwe_lo,
    u16* BT2cls, u16* BT2ew, u16* BT2we_hi, u16* BT2we_lo,
    const float* __restrict__ cls_b1, const float* __restrict__ ew_b1,
    const float* __restrict__ we_b1,  const float* __restrict__ cls_b2,
    const float* __restrict__ ew_b2,  const float* __restrict__ we_b2,
    float* b1ce, float* b1we, float* b2cls, float* b2ew, float* b2we) {
  __shared__ float t[64][65];
  const int bid = blockIdx.x;
  if (bid < 12288) {                       // ---- x -> (hi,lo) bf16 split
    int i = bid * 256 + threadIdx.x;       // 12288*256 = 16384*768/4 exact
    float4 v = ((const float4*)x)[i];
    ushort4 h, l;
    h.x = f2bf(v.x); l.x = f2bf(v.x - bf2f(h.x));
    h.y = f2bf(v.y); l.y = f2bf(v.y - bf2f(h.y));
    h.z = f2bf(v.z); l.z = f2bf(v.z - bf2f(h.z));
    h.w = f2bf(v.w); l.w = f2bf(v.w - bf2f(h.w));
    ((ushort4*)xhi)[i] = h;
    ((ushort4*)xlo)[i] = l;
    return;
  }
  if (bid < 13152) {                       // ---- LDS-tiled transpose W[768][N] -> BT[Npad][768]
    const int idx = bid - 12288;
    const int bx = idx % 12, by = (idx / 12) % 12, bz = idx / 144;
    const float* src; int N; u16* dhi; u16* dlo = nullptr;
    switch (bz) {
      case 0: src = cls_w1; N = 768; dhi = BT1; break;
      case 1: src = ew_w1;  N = 768; dhi = BT1 + 768 * 768; break;
      case 2: src = we_w1;  N = 768; dhi = BTwe_hi; dlo = BTwe_lo; break;
      case 3: src = cls_w2; N = 744; dhi = BT2cls; break;
      case 4: src = ew_w2;  N = 124; dhi = BT2ew; break;
      default: src = we_w2; N = 124; dhi = BT2we_hi; dlo = BT2we_lo; break;
    }
    const int Npad = (N + 127) & ~127;
    const int n0 = by * 64;
    if (n0 >= Npad) return;
    const int k0 = bx * 64;
    const int tx = threadIdx.x & 63, tg = threadIdx.x >> 6;
#pragma unroll
    for (int r = 0; r < 16; ++r) {
      int k = tg * 16 + r;
      int n = n0 + tx;
      t[k][tx] = (n < N) ? src[(size_t)(k0 + k) * N + n] : 0.f;   // coalesced read
    }
    __syncthreads();
#pragma unroll
    for (int r = 0; r < 16; ++r) {
      int n = n0 + tg * 16 + r;
      if (n < Npad) {
        float v = t[tx][tg * 16 + r];
        u16 h = f2bf(v);
        dhi[(size_t)n * 768 + k0 + tx] = h;                       // coalesced write
        if (dlo) dlo[(size_t)n * 768 + k0 + tx] = f2bf(v - bf2f(h));
      }
    }
    return;
  }
  // ---- bias concat/pad: 13 blocks * 256 = 3328 = 1536+768+768+128+128 exact
  int id = (bid - 13152) * 256 + threadIdx.x;
  if (id < 1536) { b1ce[id] = (id < 768) ? cls_b1[id] : ew_b1[id - 768]; return; }
  id -= 1536;
  if (id < 768) { b1we[id] = we_b1[id]; return; }
  id -= 768;
  if (id < 768) { b2cls[id] = (id < 744) ? cls_b2[id] : 0.f; return; }
  id -= 768;
  if (id < 128) { b2ew[id] = (id < 124) ? ew_b2[id] : 0.f; return; }
  id -= 128;
  if (id < 128) { b2we[id] = (id < 124) ? we_b2[id] : 0.f; return; }
}

// ---------------- GEMM core (R2-exact): 128x128 tile, BK=64, 4 waves 2x2, XOR-swizzled LDS ----------------
// LDS: logical (row, c8) at physical c8p = c8 ^ (row&7) -> conflict-free ds_read_b128 (R2: 0 conflicts).
__device__ __forceinline__ void gemm_core(
    const u16* A0, const u16* A1, const u16* A2, int lda,
    const u16* B0, const u16* B1, const u16* B2,   // pre-offset by bn*K
    int npass, int K, int bm, int tid, u16* sA, u16* sB, f32x4 acc[4][4]) {
  const int lane = tid & 63;
  const int wv = tid >> 6;
  const int wr = wv >> 1, wc = wv & 1;
  const int sr = lane >> 3;                        // staging row within 8-row group
  const int sc = (((lane & 7) ^ sr) << 3);         // swizzled source col group
  for (int p = 0; p < npass; ++p) {
    const u16* A = (p == 0) ? A0 : ((p == 1) ? A1 : A2);
    const u16* Bp = (p == 0) ? B0 : ((p == 1) ? B1 : B2);
    const u16* gA = A + (size_t)(bm + wv * 32 + sr) * lda + sc;
    const u16* gB = Bp + (size_t)(wv * 32 + sr) * K + sc;
    u16* lA = sA + (wv * 32) * 64;
    u16* lB = sB + (wv * 32) * 64;
    for (int kt = 0; kt < K; kt += 64) {
#pragma unroll
      for (int s = 0; s < 4; ++s) {
        g2l16(gA + (size_t)(s * 8) * lda + kt, lA + s * 8 * 64);
        g2l16(gB + (size_t)(s * 8) * K + kt, lB + s * 8 * 64);
      }
      __syncthreads();
#pragma unroll
      for (int ks = 0; ks < 2; ++ks) {
        const int co = ((ks * 4 + (lane >> 4)) ^ (lane & 7)) * 8;  // row&7 == lane&7 for all frags
        short8 av[4], bv[4];
#pragma unroll
        for (int i = 0; i < 4; i++)
          av[i] = *(const short8*)(sA + (wr * 64 + i * 16 + (lane & 15)) * 64 + co);
#pragma unroll
        for (int j = 0; j < 4; j++)
          bv[j] = *(const short8*)(sB + (wc * 64 + j * 16 + (lane & 15)) * 64 + co);
#pragma unroll
        for (int i = 0; i < 4; i++)
#pragma unroll
          for (int j = 0; j < 4; j++)
            acc[i][j] = __builtin_amdgcn_mfma_f32_16x16x32_bf16(av[i], bv[j], acc[i][j], 0, 0, 0);
      }
      __syncthreads();
    }
  }
}

// ---------------- packed hi/lo split core: C = Ahi*Bhi^T + Alo*Bhi^T + Ahi*Blo^T, ONE K-loop ----------------
// LDS rows pack [hi(32)|lo(32)] = 128B/row -> proven XOR-8 granule swizzle unchanged; hi/lo select
// is per-lane on the global_load_lds source address. 48 MFMA per wave per barrier-pair.
// Shared by gemm1's which_expert fc1 (R5/R6-proven) and now gemm2's which_expert fc2.
__device__ __forceinline__ void gemm_split_core(
    const u16* __restrict__ Ahi, const u16* __restrict__ Alo, int lda,
    const u16* __restrict__ Bhi, const u16* __restrict__ Blo, int ldb,  // pre-offset to tile row 0
    int K, int bm, int tid, u16* sA, u16* sB, f32x4 acc[4][4]) {
  const int lane = tid & 63;
  const int wv = tid >> 6;
  const int wr = wv >> 1, wc = wv & 1;
  const int sr = lane >> 3;                  // row within 8-row staging group
  const int gl = (lane & 7) ^ sr;            // logical granule at this lane's phys slot
  const int koff = (gl & 3) << 3;            // element offset within the 32-elem half
  const u16* Asel = (gl < 4) ? Ahi : Alo;
  const u16* Bsel = (gl < 4) ? Bhi : Blo;
  const u16* gA = Asel + (size_t)(bm + wv * 32 + sr) * lda + koff;
  const u16* gB = Bsel + (size_t)(wv * 32 + sr) * ldb + koff;
  u16* lA = sA + (wv * 32) * 64;
  u16* lB = sB + (wv * 32) * 64;

  for (int kt = 0; kt < K; kt += 32) {
#pragma unroll
    for (int s = 0; s < 4; ++s) {
      g2l16(gA + (size_t)(s * 8) * lda + kt, lA + s * 8 * 64);
      g2l16(gB + (size_t)(s * 8) * ldb + kt, lB + s * 8 * 64);
    }
    __syncthreads();
    // fragment granule: hi at (kg ^ row&7), lo at same ^ 4 -> element offset ^32
    const int coh = (((lane >> 4) ^ (lane & 7)) << 3);
    short8 ah[4], al[4], bh[4], bl[4];
#pragma unroll
    for (int i = 0; i < 4; i++) {
      const u16* p = sA + (wr * 64 + i * 16 + (lane & 15)) * 64;
      ah[i] = *(const short8*)(p + coh);
      al[i] = *(const short8*)(p + (coh ^ 32));
    }
#pragma unroll
    for (int j = 0; j < 4; j++) {
      const u16* p = sB + (wc * 64 + j * 16 + (lane & 15)) * 64;
      bh[j] = *(const short8*)(p + coh);
      bl[j] = *(const short8*)(p + (coh ^ 32));
    }
#pragma unroll
    for (int i = 0; i < 4; i++)
#pragma unroll
      for (int j = 0; j < 4; j++) {
        acc[i][j] = __builtin_amdgcn_mfma_f32_16x16x32_bf16(ah[i], bh[j], acc[i][j], 0, 0, 0);
        acc[i][j] = __builtin_amdgcn_mfma_f32_16x16x32_bf16(al[i], bh[j], acc[i][j], 0, 0, 0);
        acc[i][j] = __builtin_amdgcn_mfma_f32_16x16x32_bf16(ah[i], bl[j], acc[i][j], 0, 0, 0);
      }
    __syncthreads();
  }
}

// XCD/L2 swizzle for 128-row tiles: xcd=bid&7 owns 16 row-chunks; 8-row sub-bands, rows fastest.
__device__ __forceinline__ void decode_bid(int bid, int NC, int& bm, int& bn) {
  const int xcd = bid & 7, slot = bid >> 3;
  const int per = NC << 3;
  const int sub = slot / per, rem = slot - sub * per;
  const int colu = rem >> 3, rowIn = rem & 7;
  bm = ((xcd << 4) + (sub << 3) + rowIn) << 7;
  bn = colu << 7;
}

// ---------------- fused fc1: BOTH heads in one dispatch ----------------
// bid [0,768)    -> which_expert packed-split GEMM (heavy ~2x -> first)
// bid [768,2304) -> cls+ew GEMM (light, backfills residency gaps + tail)
__global__ __launch_bounds__(256, 4) void gemm1_fused(
    const u16* __restrict__ Ahi, const u16* __restrict__ Alo,      // xhi, xlo [16384][768]
    const u16* __restrict__ Bwe_hi, const u16* __restrict__ Bwe_lo,// we_w1^T splits [768][768]
    const u16* __restrict__ BT1,                                   // [cls_w1^T; ew_w1^T] [1536][768]
    const float* __restrict__ b1we, const float* __restrict__ b1ce,
    u16* __restrict__ out_we_hi, u16* __restrict__ out_we_lo,      // [16384][768]
    u16* __restrict__ out_ce) {                                    // [16384][1536]
  __shared__ u16 smem[2 * 128 * 64];
  u16* sA = smem;
  u16* sB = smem + 128 * 64;
  const int tid = threadIdx.x;
  const int lane = tid & 63;
  const int wr = (tid >> 6) >> 1, wc = (tid >> 6) & 1;
  const int K = 768;

  f32x4 acc[4][4];
#pragma unroll
  for (int i = 0; i < 4; i++)
#pragma unroll
    for (int j = 0; j < 4; j++) acc[i][j] = f32x4{0.f, 0.f, 0.f, 0.f};

  if (blockIdx.x < 768) {
    // ===== which_expert fc1: packed-split, gelu -> bf16 hi + lo =====
    int bm, bn;
    decode_bid(blockIdx.x, 6, bm, bn);
    gemm_split_core(Ahi, Alo, K, Bwe_hi + (size_t)bn * K, Bwe_lo + (size_t)bn * K, K,
                    K, bm, tid, sA, sB, acc);
#pragma unroll
    for (int j = 0; j < 4; j++) {
      const int col = bn + wc * 64 + j * 16 + (lane & 15);
      const float bs = b1we[col];
#pragma unroll
      for (int i = 0; i < 4; i++) {
        const int row0 = bm + wr * 64 + i * 16 + (lane >> 4) * 4;
#pragma unroll
        for (int r = 0; r < 4; r++) {
          float v = acc[i][j][r] + bs;
          const size_t idx = (size_t)(row0 + r) * 768 + col;
          float g = 0.5f * v * (1.0f + erff(v * 0.70710678118654752f));
          u16 h = f2bf(g);
          out_we_hi[idx] = h;
          out_we_lo[idx] = f2bf(g - bf2f(h));
        }
      }
    }
  } else {
    // ===== cls+ew fc1 (N=1536), gelu -> bf16 =====
    int bm, bn;
    decode_bid(blockIdx.x - 768, 12, bm, bn);
    gemm_core(Ahi, nullptr, nullptr, 768, BT1 + (size_t)bn * K, nullptr, nullptr,
              1, K, bm, tid, sA, sB, acc);
#pragma unroll
    for (int j = 0; j < 4; j++) {
      const int col = bn + wc * 64 + j * 16 + (lane & 15);
      const float bs = b1ce[col];
#pragma unroll
      for (int i = 0; i < 4; i++) {
        const int row0 = bm + wr * 64 + i * 16 + (lane >> 4) * 4;
#pragma unroll
        for (int r = 0; r < 4; r++) {
          float v = acc[i][j][r] + bs;
          float g = 0.5f * v * (1.0f + erff(v * 0.70710678118654752f));  // exact GELU
          out_ce[(size_t)(row0 + r) * 1536 + col] = f2bf(g);
        }
      }
    }
  }
}

// fused fc2, heavy-first bid order (all 1024 blocks co-resident at 4/CU):
//   bid [0,128) -> we packed-split (was 3-pass; now 24 barrier-pairs vs 36, 2/3 staging)
//   bid [128,256) -> ew ; bid [256,1024) -> cls
__global__ __launch_bounds__(256, 4) void gemm2_fused(
    const u16* __restrict__ h_cls,                  // [16384][1536]: cls cols 0..767, ew cols 768..1535
    const u16* __restrict__ hwe_hi, const u16* __restrict__ hwe_lo,
    const u16* __restrict__ BT2cls, const u16* __restrict__ BT2ew,
    const u16* __restrict__ BT2we_hi, const u16* __restrict__ BT2we_lo,
    const float* __restrict__ b2cls, const float* __restrict__ b2ew,
    const float* __restrict__ b2we,
    u16* __restrict__ Lcls, float* __restrict__ Lew, float* __restrict__ Lwe) {
  __shared__ u16 sA[128 * 64];
  __shared__ u16 sB[128 * 64];
  const int tid = threadIdx.x;
  const int lane = tid & 63;
  const int wr = (tid >> 6) >> 1, wc = (tid >> 6) & 1;

  f32x4 acc[4][4];
#pragma unroll
  for (int i = 0; i < 4; i++)
#pragma unroll
    for (int j = 0; j < 4; j++) acc[i][j] = f32x4{0.f, 0.f, 0.f, 0.f};

  const int bid = blockIdx.x;
  if (bid >= 256) {                        // ---- cls: 768 blocks, 6 col-tiles
    int bm, bn;
    decode_bid(bid - 256, 6, bm, bn);
    gemm_core(h_cls, nullptr, nullptr, 1536, BT2cls + (size_t)bn * 768, nullptr, nullptr,
              1, 768, bm, tid, sA, sB, acc);
#pragma unroll
    for (int j = 0; j < 4; j++) {
      const int col = bn + wc * 64 + j * 16 + (lane & 15);
      const float bs = b2cls[col];
#pragma unroll
      for (int i = 0; i < 4; i++) {
        const int row0 = bm + wr * 64 + i * 16 + (lane >> 4) * 4;
#pragma unroll
        for (int r = 0; r < 4; r++)
          Lcls[(size_t)(row0 + r) * 768 + col] = f2bf(acc[i][j][r] + bs);
      }
    }
  } else {                                 // ---- heavy: we [0,128), ew [128,256)
    const bool is_we = (bid < 128);
    const int r = is_we ? bid : bid - 128;
    const int bm = (((r & 7) << 4) + (r >> 3)) << 7;   // xcd owns 16 row-chunks
    if (is_we)
      gemm_split_core(hwe_hi, hwe_lo, 768, BT2we_hi, BT2we_lo, 768,
                      768, bm, tid, sA, sB, acc);
    else
      gemm_core(h_cls + 768, nullptr, nullptr, 1536, BT2ew, nullptr, nullptr,
                1, 768, bm, tid, sA, sB, acc);
    float* o = is_we ? Lwe : Lew;
    const float* bp = is_we ? b2we : b2ew;
#pragma unroll
    for (int j = 0; j < 4; j++) {
      const int col = wc * 64 + j * 16 + (lane & 15);
      const float bs = bp[col];
#pragma unroll
      for (int i = 0; i < 4; i++) {
        const int row0 = bm + wr * 64 + i * 16 + (lane >> 4) * 4;
#pragma unroll
        for (int r2 = 0; r2 < 4; r2++)
          o[(size_t)(row0 + r2) * 128 + col] = acc[i][j][r2] + bs;
      }
    }
  }
}

// ---------------- finalize: rank-select mask (== reference threshold), softmaxes, mixture ----------------
// keep_i  <=>  which_i >= n-th largest  <=>  #{j : w_j > w_i} < n   (ties keep both, same as ref)
__global__ __launch_bounds__(256) void finalize(
    const u16* __restrict__ Lcls,   // bf16 [B][768], expert e at cols e*6..e*6+5
    const float* __restrict__ Lwe,  // f32 [B][128]
    const float* __restrict__ Lew,  // f32 [B][128]
    const int* __restrict__ nexp, float* __restrict__ out) {
  const int bid = blockIdx.x;
  const int g = ((bid & 7) << 9) + (bid >> 3);      // XCD band matches gemm2's row mapping
  const int b = (g << 2) + (int)(threadIdx.x >> 6); // 4 rows/block, one wave each
  const int lane = threadIdx.x & 63;
  const float NEG = -3.0e38f;
  const float w0 = (lane < 124) ? Lwe[(size_t)b * 128 + lane] : NEG;
  const float w1 = (lane < 60) ? Lwe[(size_t)b * 128 + 64 + lane] : NEG;
  int r0 = 0, r1 = 0;
#pragma unroll
  for (int j = 0; j < 64; ++j) {
    float v = __shfl(w0, j, 64);
    r0 += (v > w0); r1 += (v > w1);
  }
#pragma unroll
  for (int j = 0; j < 64; ++j) {
    float v = __shfl(w1, j, 64);
    r0 += (v > w0); r1 += (v > w1);
  }
  int n = nexp[b];
  n = n < 1 ? 1 : (n > 124 ? 124 : n);
  const bool k0 = (lane < 124) && (r0 < n);
  const bool k1 = (lane < 60) && (r1 < n);
  float l0 = k0 ? Lew[(size_t)b * 128 + lane] : NEG;
  float l1 = k1 ? Lew[(size_t)b * 128 + 64 + lane] : NEG;
  float mx = fmaxf(l0, l1);
#pragma unroll
  for (int o = 32; o > 0; o >>= 1) mx = fmaxf(mx, __shfl_xor(mx, o, 64));
  float e0 = k0 ? __expf(l0 - mx) : 0.f;
  float e1 = k1 ? __expf(l1 - mx) : 0.f;
  float S = e0 + e1;
#pragma unroll
  for (int o = 32; o > 0; o >>= 1) S += __shfl_xor(S, o, 64);
  float a0 = 0, a1 = 0, a2 = 0, a3 = 0, a4 = 0, a5 = 0;
#pragma unroll
  for (int h = 0; h < 2; ++h) {
    int e = lane + h * 64;
    float we = h ? e1 : e0;
    if (we > 0.f) {
      const u16* lp = Lcls + (size_t)b * 768 + e * 6;
      float c0 = bf2f(lp[0]), c1 = bf2f(lp[1]), c2 = bf2f(lp[2]);
      float c3 = bf2f(lp[3]), c4 = bf2f(lp[4]), c5 = bf2f(lp[5]);
      float m = fmaxf(fmaxf(fmaxf(c0, c1), fmaxf(c2, c3)), fmaxf(c4, c5));
      float p0 = __expf(c0 - m), p1 = __expf(c1 - m), p2 = __expf(c2 - m);
      float p3 = __expf(c3 - m), p4 = __expf(c4 - m), p5 = __expf(c5 - m);
      float inv = we / (p0 + p1 + p2 + p3 + p4 + p5);
      a0 += p0 * inv; a1 += p1 * inv; a2 += p2 * inv;
      a3 += p3 * inv; a4 += p4 * inv; a5 += p5 * inv;
    }
  }
#pragma unroll
  for (int o = 32; o > 0; o >>= 1) {
    a0 += __shfl_xor(a0, o, 64); a1 += __shfl_xor(a1, o, 64);
    a2 += __shfl_xor(a2, o, 64); a3 += __shfl_xor(a3, o, 64);
    a4 += __shfl_xor(a4, o, 64); a5 += __shfl_xor(a5, o, 64);
  }
  if (lane < 6) {
    float v = (lane == 0) ? a0 : (lane == 1) ? a1 : (lane == 2) ? a2
              : (lane == 3) ? a3 : (lane == 4) ? a4 : a5;
    out[(size_t)b * 6 + lane] = v / S;
  }
}

__global__ void fill_sentinel(float* out, int n, float v) {
  int i = blockIdx.x * 256 + threadIdx.x;
  if (i < n) out[i] = v;
}

extern "C" void kernel_launch(void* const* d_in, const int* in_sizes, int n_in,
                              void* d_out, int out_size, void* d_ws, size_t ws_size,
                              hipStream_t stream) {
  const float* x = (const float*)d_in[0];
  const int* nexp = (const int*)d_in[1];
  const float* cls_w1 = (const float*)d_in[2];
  const float* cls_b1 = (const float*)d_in[3];
  const float* cls_w2 = (const float*)d_in[4];
  const float* cls_b2 = (const float*)d_in[5];
  const float* we_w1 = (const float*)d_in[6];
  const float* we_b1 = (const float*)d_in[7];
  const float* we_w2 = (const float*)d_in[8];
  const float* we_b2 = (const float*)d_in[9];
  const float* ew_w1 = (const float*)d_in[10];
  const float* ew_b1 = (const float*)d_in[11];
  const float* ew_w2 = (const float*)d_in[12];
  const float* ew_b2 = (const float*)d_in[13];
  float* out = (float*)d_out;
  char* ws = (char*)d_ws;

  if (ws_size < WS_NEED) {  // diagnosable failure: absmax ~12345
    fill_sentinel<<<(out_size + 255) / 256, 256, 0, stream>>>(out, out_size, 12345.0f);
    return;
  }

  u16* xhi = (u16*)(ws + OFF_XHI);
  u16* xlo = (u16*)(ws + OFF_XLO);
  u16* Lcls = (u16*)(ws + OFF_LCLS);
  float* Lwe = (float*)(ws + OFF_LWE);
  float* Lew = (float*)(ws + OFF_LEW);
  u16* BT1 = (u16*)(ws + OFF_BT1);
  u16* BTwe_hi = (u16*)(ws + OFF_BTWE_HI);
  u16* BTwe_lo = (u16*)(ws + OFF_BTWE_LO);
  u16* BT2cls = (u16*)(ws + OFF_BT2CLS);
  u16* BT2ew = (u16*)(ws + OFF_BT2EW);
  u16* BT2we_hi = (u16*)(ws + OFF_BT2WE_HI);
  u16* BT2we_lo = (u16*)(ws + OFF_BT2WE_LO);
  float* b1ce = (float*)(ws + OFF_B1CE);
  float* b1we = (float*)(ws + OFF_B1WE);
  float* b2cls = (float*)(ws + OFF_B2CLS);
  float* b2ew = (float*)(ws + OFF_B2EW);
  float* b2we = (float*)(ws + OFF_B2WE);
  u16* h_clsew = (u16*)(ws + OFF_HCLSEW);
  u16* h_we_hi = (u16*)(ws + OFF_HWE_HI);
  u16* h_we_lo = (u16*)(ws + OFF_HWE_LO);

  prep_all<<<13165, 256, 0, stream>>>(x, xhi, xlo,
                                      cls_w1, ew_w1, we_w1, cls_w2, ew_w2, we_w2,
                                      BT1, BTwe_hi, BTwe_lo, BT2cls, BT2ew, BT2we_hi, BT2we_lo,
                                      cls_b1, ew_b1, we_b1, cls_b2, ew_b2, we_b2,
                                      b1ce, b1we, b2cls, b2ew, b2we);
  // fc1 BOTH heads in one dispatch: heavy packed-split we blocks first, cls/ew backfills
  gemm1_fused<<<2304, 256, 0, stream>>>(xhi, xlo, BTwe_hi, BTwe_lo, BT1,
                                        b1we, b1ce, h_we_hi, h_we_lo, h_clsew);
  // fc2 all three heads in one dispatch, heavy (packed-split we) blocks first
  gemm2_fused<<<1024, 256, 0, stream>>>(h_clsew, h_we_hi, h_we_lo,
                                        BT2cls, BT2ew, BT2we_hi, BT2we_lo,
                                        b2cls, b2ew, b2we, Lcls, Lew, Lwe);
  finalize<<<4096, 256, 0, stream>>>(Lcls, Lwe, Lew, nexp, out);
}

// Round 8
// 333.937 us; speedup vs baseline: 1.2817x; 1.0368x over previous
//
#include <hip/hip_runtime.h>
#include <stdint.h>

typedef unsigned short u16;
typedef short short8 __attribute__((ext_vector_type(8)));
typedef float f32x4 __attribute__((ext_vector_type(4)));

// Problem sizes: B=16384, D=768, E=124 (pad 128), C=6, E*C=744 (pad 768)
#define NB 16384

// ---- workspace layout (bytes) ----
#define OFF_XHI      0ull            // bf16 [16384][768]
#define OFF_XLO      25165824ull     // bf16 [16384][768]
#define OFF_LCLS     0ull            // aliases XHI: bf16 [16384][768] class logits (cols 0..743 real)
#define OFF_LWE_P0   25165824ull     // f32 [16384][128] which_expert partial hi*Whi (+bias)  (aliases XLO)
#define OFF_LWE_P1   33554432ull     // f32 [16384][128] partial lo*Whi
#define OFF_LWE_P2   41943040ull     // f32 [16384][128] partial hi*Wlo
#define OFF_BT1      50331648ull     // bf16 [1536][768]  (cls_w1^T ; ew_w1^T)  [dead after gemm1]
#define OFF_LEWB     50331648ull     // bf16 [16384][128] ew logits (aliases BT1 region, written in gemm2)
#define OFF_BTWE_HI  52690944ull     // bf16 [768][768]
#define OFF_BTWE_LO  53870592ull
#define OFF_BT2CLS   55050240ull     // bf16 [768][768] (744 real rows, padded w/ 0)
#define OFF_BT2EW    56229888ull     // bf16 [128][768]
#define OFF_BT2WE_HI 56426496ull
#define OFF_BT2WE_LO 56623104ull
#define OFF_B1CE     56819712ull     // f32 [1536]
#define OFF_B1WE     56825856ull     // f32 [768]
#define OFF_B2CLS    56828928ull     // f32 [768]
#define OFF_B2EW     56832000ull     // f32 [128]
#define OFF_B2WE     56832512ull     // f32 [128]
#define OFF_HCLSEW   56833024ull     // bf16 [16384][1536] gelu(h) for cls|ew
#define OFF_HWE_HI   107164672ull    // bf16 [16384][768]
#define OFF_HWE_LO   132330496ull    // bf16 [16384][768]
#define WS_NEED      157496320ull

__device__ __forceinline__ u16 f2bf(float f) {          // RNE f32->bf16
  uint32_t u = __float_as_uint(f);
  u += 0x7fffu + ((u >> 16) & 1u);
  return (u16)(u >> 16);
}
__device__ __forceinline__ float bf2f(u16 h) {
  return __uint_as_float(((uint32_t)h) << 16);
}
__device__ __forceinline__ void g2l16(const u16* g, u16* l) {
  // async global->LDS, 16B/lane; LDS dest = wave-uniform base + lane*16 (HW rule).
  // Global side is a normal per-lane address -> per-lane source permutation is legal.
  __builtin_amdgcn_global_load_lds(
      (__attribute__((address_space(1))) void*)(u16*)g,
      (__attribute__((address_space(3))) void*)l, 16, 0, 0);
}

// ---------------- merged prep: cvt_x split + weight transposes + bias concat ----------------
// grid layout: [0,12288) cvt_x ; [12288,13152) transpose (12x12x6) ; [13152,13165) bias
__global__ void prep_all(
    const float* __restrict__ x, u16* __restrict__ xhi, u16* __restrict__ xlo,
    const float* __restrict__ cls_w1, const float* __restrict__ ew_w1,
    const float* __restrict__ we_w1,  const float* __restrict__ cls_w2,
    const float* __restrict__ ew_w2,  const float* __restrict__ we_w2,
    u16* BT1, u16* BTwe_hi, u16* BTwe_lo,
    u16* BT2cls, u16* BT2ew, u16* BT2we_hi, u16* BT2we_lo,
    const float* __restrict__ cls_b1, const float* __restrict__ ew_b1,
    const float* __restrict__ we_b1,  const float* __restrict__ cls_b2,
    const float* __restrict__ ew_b2,  const float* __restrict__ we_b2,
    float* b1ce, float* b1we, float* b2cls, float* b2ew, float* b2we) {
  __shared__ float t[64][65];
  const int bid = blockIdx.x;
  if (bid < 12288) {                       // ---- x -> (hi,lo) bf16 split
    int i = bid * 256 + threadIdx.x;       // 12288*256 = 16384*768/4 exact
    float4 v = ((const float4*)x)[i];
    ushort4 h, l;
    h.x = f2bf(v.x); l.x = f2bf(v.x - bf2f(h.x));
    h.y = f2bf(v.y); l.y = f2bf(v.y - bf2f(h.y));
    h.z = f2bf(v.z); l.z = f2bf(v.z - bf2f(h.z));
    h.w = f2bf(v.w); l.w = f2bf(v.w - bf2f(h.w));
    ((ushort4*)xhi)[i] = h;
    ((ushort4*)xlo)[i] = l;
    return;
  }
  if (bid < 13152) {                       // ---- LDS-tiled transpose W[768][N] -> BT[Npad][768]
    const int idx = bid - 12288;
    const int bx = idx % 12, by = (idx / 12) % 12, bz = idx / 144;
    const float* src; int N; u16* dhi; u16* dlo = nullptr;
    switch (bz) {
      case 0: src = cls_w1; N = 768; dhi = BT1; break;
      case 1: src = ew_w1;  N = 768; dhi = BT1 + 768 * 768; break;
      case 2: src = we_w1;  N = 768; dhi = BTwe_hi; dlo = BTwe_lo; break;
      case 3: src = cls_w2; N = 744; dhi = BT2cls; break;
      case 4: src = ew_w2;  N = 124; dhi = BT2ew; break;
      default: src = we_w2; N = 124; dhi = BT2we_hi; dlo = BT2we_lo; break;
    }
    const int Npad = (N + 127) & ~127;
    const int n0 = by * 64;
    if (n0 >= Npad) return;
    const int k0 = bx * 64;
    const int tx = threadIdx.x & 63, tg = threadIdx.x >> 6;
#pragma unroll
    for (int r = 0; r < 16; ++r) {
      int k = tg * 16 + r;
      int n = n0 + tx;
      t[k][tx] = (n < N) ? src[(size_t)(k0 + k) * N + n] : 0.f;   // coalesced read
    }
    __syncthreads();
#pragma unroll
    for (int r = 0; r < 16; ++r) {
      int n = n0 + tg * 16 + r;
      if (n < Npad) {
        float v = t[tx][tg * 16 + r];
        u16 h = f2bf(v);
        dhi[(size_t)n * 768 + k0 + tx] = h;                       // coalesced write
        if (dlo) dlo[(size_t)n * 768 + k0 + tx] = f2bf(v - bf2f(h));
      }
    }
    return;
  }
  // ---- bias concat/pad: 13 blocks * 256 = 3328 = 1536+768+768+128+128 exact
  int id = (bid - 13152) * 256 + threadIdx.x;
  if (id < 1536) { b1ce[id] = (id < 768) ? cls_b1[id] : ew_b1[id - 768]; return; }
  id -= 1536;
  if (id < 768) { b1we[id] = we_b1[id]; return; }
  id -= 768;
  if (id < 768) { b2cls[id] = (id < 744) ? cls_b2[id] : 0.f; return; }
  id -= 768;
  if (id < 128) { b2ew[id] = (id < 124) ? ew_b2[id] : 0.f; return; }
  id -= 128;
  if (id < 128) { b2we[id] = (id < 124) ? we_b2[id] : 0.f; return; }
}

// ---------------- GEMM core (R2-exact): 128x128 tile, BK=64, 4 waves 2x2, XOR-swizzled LDS ----------------
// LDS: logical (row, c8) at physical c8p = c8 ^ (row&7) -> conflict-free ds_read_b128 (R2: 0 conflicts).
__device__ __forceinline__ void gemm_core(
    const u16* A0, const u16* A1, const u16* A2, int lda,
    const u16* B0, const u16* B1, const u16* B2,   // pre-offset by bn*K
    int npass, int K, int bm, int tid, u16* sA, u16* sB, f32x4 acc[4][4]) {
  const int lane = tid & 63;
  const int wv = tid >> 6;
  const int wr = wv >> 1, wc = wv & 1;
  const int sr = lane >> 3;                        // staging row within 8-row group
  const int sc = (((lane & 7) ^ sr) << 3);         // swizzled source col group
  for (int p = 0; p < npass; ++p) {
    const u16* A = (p == 0) ? A0 : ((p == 1) ? A1 : A2);
    const u16* Bp = (p == 0) ? B0 : ((p == 1) ? B1 : B2);
    const u16* gA = A + (size_t)(bm + wv * 32 + sr) * lda + sc;
    const u16* gB = Bp + (size_t)(wv * 32 + sr) * K + sc;
    u16* lA = sA + (wv * 32) * 64;
    u16* lB = sB + (wv * 32) * 64;
    for (int kt = 0; kt < K; kt += 64) {
#pragma unroll
      for (int s = 0; s < 4; ++s) {
        g2l16(gA + (size_t)(s * 8) * lda + kt, lA + s * 8 * 64);
        g2l16(gB + (size_t)(s * 8) * K + kt, lB + s * 8 * 64);
      }
      __syncthreads();
#pragma unroll
      for (int ks = 0; ks < 2; ++ks) {
        const int co = ((ks * 4 + (lane >> 4)) ^ (lane & 7)) * 8;  // row&7 == lane&7 for all frags
        short8 av[4], bv[4];
#pragma unroll
        for (int i = 0; i < 4; i++)
          av[i] = *(const short8*)(sA + (wr * 64 + i * 16 + (lane & 15)) * 64 + co);
#pragma unroll
        for (int j = 0; j < 4; j++)
          bv[j] = *(const short8*)(sB + (wc * 64 + j * 16 + (lane & 15)) * 64 + co);
#pragma unroll
        for (int i = 0; i < 4; i++)
#pragma unroll
          for (int j = 0; j < 4; j++)
            acc[i][j] = __builtin_amdgcn_mfma_f32_16x16x32_bf16(av[i], bv[j], acc[i][j], 0, 0, 0);
      }
      __syncthreads();
    }
  }
}

// ---------------- packed hi/lo split core: C = Ahi*Bhi^T + Alo*Bhi^T + Ahi*Blo^T, ONE K-loop ----------------
// LDS rows pack [hi(32)|lo(32)] = 128B/row -> proven XOR-8 granule swizzle unchanged; hi/lo select
// is per-lane on the global_load_lds source address. 48 MFMA per wave per barrier-pair.
// Used by gemm1's which_expert fc1 (R5-R7 proven).
__device__ __forceinline__ void gemm_split_core(
    const u16* __restrict__ Ahi, const u16* __restrict__ Alo, int lda,
    const u16* __restrict__ Bhi, const u16* __restrict__ Blo, int ldb,  // pre-offset to tile row 0
    int K, int bm, int tid, u16* sA, u16* sB, f32x4 acc[4][4]) {
  const int lane = tid & 63;
  const int wv = tid >> 6;
  const int wr = wv >> 1, wc = wv & 1;
  const int sr = lane >> 3;                  // row within 8-row staging group
  const int gl = (lane & 7) ^ sr;            // logical granule at this lane's phys slot
  const int koff = (gl & 3) << 3;            // element offset within the 32-elem half
  const u16* Asel = (gl < 4) ? Ahi : Alo;
  const u16* Bsel = (gl < 4) ? Bhi : Blo;
  const u16* gA = Asel + (size_t)(bm + wv * 32 + sr) * lda + koff;
  const u16* gB = Bsel + (size_t)(wv * 32 + sr) * ldb + koff;
  u16* lA = sA + (wv * 32) * 64;
  u16* lB = sB + (wv * 32) * 64;

  for (int kt = 0; kt < K; kt += 32) {
#pragma unroll
    for (int s = 0; s < 4; ++s) {
      g2l16(gA + (size_t)(s * 8) * lda + kt, lA + s * 8 * 64);
      g2l16(gB + (size_t)(s * 8) * ldb + kt, lB + s * 8 * 64);
    }
    __syncthreads();
    // fragment granule: hi at (kg ^ row&7), lo at same ^ 4 -> element offset ^32
    const int coh = (((lane >> 4) ^ (lane & 7)) << 3);
    short8 ah[4], al[4], bh[4], bl[4];
#pragma unroll
    for (int i = 0; i < 4; i++) {
      const u16* p = sA + (wr * 64 + i * 16 + (lane & 15)) * 64;
      ah[i] = *(const short8*)(p + coh);
      al[i] = *(const short8*)(p + (coh ^ 32));
    }
#pragma unroll
    for (int j = 0; j < 4; j++) {
      const u16* p = sB + (wc * 64 + j * 16 + (lane & 15)) * 64;
      bh[j] = *(const short8*)(p + coh);
      bl[j] = *(const short8*)(p + (coh ^ 32));
    }
#pragma unroll
    for (int i = 0; i < 4; i++)
#pragma unroll
      for (int j = 0; j < 4; j++) {
        acc[i][j] = __builtin_amdgcn_mfma_f32_16x16x32_bf16(ah[i], bh[j], acc[i][j], 0, 0, 0);
        acc[i][j] = __builtin_amdgcn_mfma_f32_16x16x32_bf16(al[i], bh[j], acc[i][j], 0, 0, 0);
        acc[i][j] = __builtin_amdgcn_mfma_f32_16x16x32_bf16(ah[i], bl[j], acc[i][j], 0, 0, 0);
      }
    __syncthreads();
  }
}

// XCD/L2 swizzle for 128-row tiles: xcd=bid&7 owns 16 row-chunks; 8-row sub-bands, rows fastest.
__device__ __forceinline__ void decode_bid(int bid, int NC, int& bm, int& bn) {
  const int xcd = bid & 7, slot = bid >> 3;
  const int per = NC << 3;
  const int sub = slot / per, rem = slot - sub * per;
  const int colu = rem >> 3, rowIn = rem & 7;
  bm = ((xcd << 4) + (sub << 3) + rowIn) << 7;
  bn = colu << 7;
}

// ---------------- fused fc1: BOTH heads in one dispatch ----------------
// bid [0,768)    -> which_expert packed-split GEMM (heavy ~3x -> first)
// bid [768,2304) -> cls+ew GEMM (light, backfills residency gaps + tail)
__global__ __launch_bounds__(256, 4) void gemm1_fused(
    const u16* __restrict__ Ahi, const u16* __restrict__ Alo,      // xhi, xlo [16384][768]
    const u16* __restrict__ Bwe_hi, const u16* __restrict__ Bwe_lo,// we_w1^T splits [768][768]
    const u16* __restrict__ BT1,                                   // [cls_w1^T; ew_w1^T] [1536][768]
    const float* __restrict__ b1we, const float* __restrict__ b1ce,
    u16* __restrict__ out_we_hi, u16* __restrict__ out_we_lo,      // [16384][768]
    u16* __restrict__ out_ce) {                                    // [16384][1536]
  __shared__ u16 smem[2 * 128 * 64];
  u16* sA = smem;
  u16* sB = smem + 128 * 64;
  const int tid = threadIdx.x;
  const int lane = tid & 63;
  const int wr = (tid >> 6) >> 1, wc = (tid >> 6) & 1;
  const int K = 768;

  f32x4 acc[4][4];
#pragma unroll
  for (int i = 0; i < 4; i++)
#pragma unroll
    for (int j = 0; j < 4; j++) acc[i][j] = f32x4{0.f, 0.f, 0.f, 0.f};

  if (blockIdx.x < 768) {
    // ===== which_expert fc1: packed-split, gelu -> bf16 hi + lo =====
    int bm, bn;
    decode_bid(blockIdx.x, 6, bm, bn);
    gemm_split_core(Ahi, Alo, K, Bwe_hi + (size_t)bn * K, Bwe_lo + (size_t)bn * K, K,
                    K, bm, tid, sA, sB, acc);
#pragma unroll
    for (int j = 0; j < 4; j++) {
      const int col = bn + wc * 64 + j * 16 + (lane & 15);
      const float bs = b1we[col];
#pragma unroll
      for (int i = 0; i < 4; i++) {
        const int row0 = bm + wr * 64 + i * 16 + (lane >> 4) * 4;
#pragma unroll
        for (int r = 0; r < 4; r++) {
          float v = acc[i][j][r] + bs;
          const size_t idx = (size_t)(row0 + r) * 768 + col;
          float g = 0.5f * v * (1.0f + erff(v * 0.70710678118654752f));
          u16 h = f2bf(g);
          out_we_hi[idx] = h;
          out_we_lo[idx] = f2bf(g - bf2f(h));
        }
      }
    }
  } else {
    // ===== cls+ew fc1 (N=1536), gelu -> bf16 =====
    int bm, bn;
    decode_bid(blockIdx.x - 768, 12, bm, bn);
    gemm_core(Ahi, nullptr, nullptr, 768, BT1 + (size_t)bn * K, nullptr, nullptr,
              1, K, bm, tid, sA, sB, acc);
#pragma unroll
    for (int j = 0; j < 4; j++) {
      const int col = bn + wc * 64 + j * 16 + (lane & 15);
      const float bs = b1ce[col];
#pragma unroll
      for (int i = 0; i < 4; i++) {
        const int row0 = bm + wr * 64 + i * 16 + (lane >> 4) * 4;
#pragma unroll
        for (int r = 0; r < 4; r++) {
          float v = acc[i][j][r] + bs;
          float g = 0.5f * v * (1.0f + erff(v * 0.70710678118654752f));  // exact GELU
          out_ce[(size_t)(row0 + r) * 1536 + col] = f2bf(g);
        }
      }
    }
  }
}

// fused fc2, straggler-free block plan (R8): all blocks <= 1 cls-unit.
//   bid [0,768)     -> cls (1u, 24 K-tiles)
//   bid [768,896)   -> ew  (1u) -> bf16 Lew
//   bid [896,1280)  -> we pass-GEMMs (0.5u, 12 K-tiles): pass p=(bid-896)/128 in {0,1,2}
//                      p0 = hi*Whi + bias, p1 = lo*Whi, p2 = hi*Wlo -> f32 partials
//   First 1024 bids fill capacity; last 256 half-unit we blocks backfill the drain.
//   (bid-896) keeps XCD = r&7 -> all 3 passes of a row-chunk share an XCD's L2.
__global__ __launch_bounds__(256, 4) void gemm2_fused(
    const u16* __restrict__ h_cls,                  // [16384][1536]: cls cols 0..767, ew cols 768..1535
    const u16* __restrict__ hwe_hi, const u16* __restrict__ hwe_lo,
    const u16* __restrict__ BT2cls, const u16* __restrict__ BT2ew,
    const u16* __restrict__ BT2we_hi, const u16* __restrict__ BT2we_lo,
    const float* __restrict__ b2cls, const float* __restrict__ b2ew,
    const float* __restrict__ b2we,
    u16* __restrict__ Lcls, u16* __restrict__ LewB,
    float* __restrict__ p0, float* __restrict__ p1, float* __restrict__ p2) {
  __shared__ u16 sA[128 * 64];
  __shared__ u16 sB[128 * 64];
  const int tid = threadIdx.x;
  const int lane = tid & 63;
  const int wr = (tid >> 6) >> 1, wc = (tid >> 6) & 1;

  f32x4 acc[4][4];
#pragma unroll
  for (int i = 0; i < 4; i++)
#pragma unroll
    for (int j = 0; j < 4; j++) acc[i][j] = f32x4{0.f, 0.f, 0.f, 0.f};

  const int bid = blockIdx.x;
  if (bid < 768) {                         // ---- cls: 6 col-tiles
    int bm, bn;
    decode_bid(bid, 6, bm, bn);
    gemm_core(h_cls, nullptr, nullptr, 1536, BT2cls + (size_t)bn * 768, nullptr, nullptr,
              1, 768, bm, tid, sA, sB, acc);
#pragma unroll
    for (int j = 0; j < 4; j++) {
      const int col = bn + wc * 64 + j * 16 + (lane & 15);
      const float bs = b2cls[col];
#pragma unroll
      for (int i = 0; i < 4; i++) {
        const int row0 = bm + wr * 64 + i * 16 + (lane >> 4) * 4;
#pragma unroll
        for (int r = 0; r < 4; r++)
          Lcls[(size_t)(row0 + r) * 768 + col] = f2bf(acc[i][j][r] + bs);
      }
    }
  } else if (bid < 896) {                  // ---- ew (K=1536) -> bf16
    const int r = bid - 768;
    const int bm = (((r & 7) << 4) + (r >> 3)) << 7;
    gemm_core(h_cls + 768, nullptr, nullptr, 1536, BT2ew, nullptr, nullptr,
              1, 768, bm, tid, sA, sB, acc);
#pragma unroll
    for (int j = 0; j < 4; j++) {
      const int col = wc * 64 + j * 16 + (lane & 15);
      const float bs = b2ew[col];
#pragma unroll
      for (int i = 0; i < 4; i++) {
        const int row0 = bm + wr * 64 + i * 16 + (lane >> 4) * 4;
#pragma unroll
        for (int r2 = 0; r2 < 4; r2++)
          LewB[(size_t)(row0 + r2) * 128 + col] = f2bf(acc[i][j][r2] + bs);
      }
    }
  } else {                                 // ---- we pass-GEMMs -> f32 partials
    const int q = bid - 896;
    const int pass = q >> 7;               // 0..2 (q/128)
    const int r = q & 127;
    const int bm = (((r & 7) << 4) + (r >> 3)) << 7;
    const u16* A = (pass == 1) ? hwe_lo : hwe_hi;                 // p0,p2: hi ; p1: lo
    const u16* Bp = (pass == 2) ? BT2we_lo : BT2we_hi;            // p0,p1: Whi ; p2: Wlo
    gemm_core(A, nullptr, nullptr, 768, Bp, nullptr, nullptr,
              1, 768, bm, tid, sA, sB, acc);
    float* o = (pass == 0) ? p0 : ((pass == 1) ? p1 : p2);
#pragma unroll
    for (int j = 0; j < 4; j++) {
      const int col = wc * 64 + j * 16 + (lane & 15);
      const float bs = (pass == 0) ? b2we[col] : 0.f;             // bias only in p0
#pragma unroll
      for (int i = 0; i < 4; i++) {
        const int row0 = bm + wr * 64 + i * 16 + (lane >> 4) * 4;
#pragma unroll
        for (int r2 = 0; r2 < 4; r2++)
          o[(size_t)(row0 + r2) * 128 + col] = acc[i][j][r2] + bs;
      }
    }
  }
}

// ---------------- finalize: rank-select mask (== reference threshold), softmaxes, mixture ----------------
// which_expert = p0 + p1 + p2 (deterministic f32 sum of split partials).
// keep_i  <=>  which_i >= n-th largest  <=>  #{j : w_j > w_i} < n   (ties keep both, same as ref)
__global__ __launch_bounds__(256) void finalize(
    const u16* __restrict__ Lcls,   // bf16 [B][768], expert e at cols e*6..e*6+5
    const float* __restrict__ p0, const float* __restrict__ p1,
    const float* __restrict__ p2,   // f32 [B][128] which_expert partials
    const u16* __restrict__ LewB,   // bf16 [B][128]
    const int* __restrict__ nexp, float* __restrict__ out) {
  const int bid = blockIdx.x;
  const int g = ((bid & 7) << 9) + (bid >> 3);      // XCD band matches gemm2's row mapping
  const int b = (g << 2) + (int)(threadIdx.x >> 6); // 4 rows/block, one wave each
  const int lane = threadIdx.x & 63;
  const float NEG = -3.0e38f;
  const size_t base = (size_t)b * 128;
  const float w0 = (lane < 124) ? (p0[base + lane] + p1[base + lane] + p2[base + lane]) : NEG;
  const float w1 = (lane < 60) ? (p0[base + 64 + lane] + p1[base + 64 + lane] + p2[base + 64 + lane]) : NEG;
  int r0 = 0, r1 = 0;
#pragma unroll
  for (int j = 0; j < 64; ++j) {
    float v = __shfl(w0, j, 64);
    r0 += (v > w0); r1 += (v > w1);
  }
#pragma unroll
  for (int j = 0; j < 64; ++j) {
    float v = __shfl(w1, j, 64);
    r0 += (v > w0); r1 += (v > w1);
  }
  int n = nexp[b];
  n = n < 1 ? 1 : (n > 124 ? 124 : n);
  const bool k0 = (lane < 124) && (r0 < n);
  const bool k1 = (lane < 60) && (r1 < n);
  float l0 = k0 ? bf2f(LewB[base + lane]) : NEG;
  float l1 = k1 ? bf2f(LewB[base + 64 + lane]) : NEG;
  float mx = fmaxf(l0, l1);
#pragma unroll
  for (int o = 32; o > 0; o >>= 1) mx = fmaxf(mx, __shfl_xor(mx, o, 64));
  float e0 = k0 ? __expf(l0 - mx) : 0.f;
  float e1 = k1 ? __expf(l1 - mx) : 0.f;
  float S = e0 + e1;
#pragma unroll
  for (int o = 32; o > 0; o >>= 1) S += __shfl_xor(S, o, 64);
  float a0 = 0, a1 = 0, a2 = 0, a3 = 0, a4 = 0, a5 = 0;
#pragma unroll
  for (int h = 0; h < 2; ++h) {
    int e = lane + h * 64;
    float we = h ? e1 : e0;
    if (we > 0.f) {
      const u16* lp = Lcls + (size_t)b * 768 + e * 6;
      float c0 = bf2f(lp[0]), c1 = bf2f(lp[1]), c2 = bf2f(lp[2]);
      float c3 = bf2f(lp[3]), c4 = bf2f(lp[4]), c5 = bf2f(lp[5]);
      float m = fmaxf(fmaxf(fmaxf(c0, c1), fmaxf(c2, c3)), fmaxf(c4, c5));
      float q0 = __expf(c0 - m), q1 = __expf(c1 - m), q2 = __expf(c2 - m);
      float q3 = __expf(c3 - m), q4 = __expf(c4 - m), q5 = __expf(c5 - m);
      float inv = we / (q0 + q1 + q2 + q3 + q4 + q5);
      a0 += q0 * inv; a1 += q1 * inv; a2 += q2 * inv;
      a3 += q3 * inv; a4 += q4 * inv; a5 += q5 * inv;
    }
  }
#pragma unroll
  for (int o = 32; o > 0; o >>= 1) {
    a0 += __shfl_xor(a0, o, 64); a1 += __shfl_xor(a1, o, 64);
    a2 += __shfl_xor(a2, o, 64); a3 += __shfl_xor(a3, o, 64);
    a4 += __shfl_xor(a4, o, 64); a5 += __shfl_xor(a5, o, 64);
  }
  if (lane < 6) {
    float v = (lane == 0) ? a0 : (lane == 1) ? a1 : (lane == 2) ? a2
              : (lane == 3) ? a3 : (lane == 4) ? a4 : a5;
    out[(size_t)b * 6 + lane] = v / S;
  }
}

__global__ void fill_sentinel(float* out, int n, float v) {
  int i = blockIdx.x * 256 + threadIdx.x;
  if (i < n) out[i] = v;
}

extern "C" void kernel_launch(void* const* d_in, const int* in_sizes, int n_in,
                              void* d_out, int out_size, void* d_ws, size_t ws_size,
                              hipStream_t stream) {
  const float* x = (const float*)d_in[0];
  const int* nexp = (const int*)d_in[1];
  const float* cls_w1 = (const float*)d_in[2];
  const float* cls_b1 = (const float*)d_in[3];
  const float* cls_w2 = (const float*)d_in[4];
  const float* cls_b2 = (const float*)d_in[5];
  const float* we_w1 = (const float*)d_in[6];
  const float* we_b1 = (const float*)d_in[7];
  const float* we_w2 = (const float*)d_in[8];
  const float* we_b2 = (const float*)d_in[9];
  const float* ew_w1 = (const float*)d_in[10];
  const float* ew_b1 = (const float*)d_in[11];
  const float* ew_w2 = (const float*)d_in[12];
  const float* ew_b2 = (const float*)d_in[13];
  float* out = (float*)d_out;
  char* ws = (char*)d_ws;

  if (ws_size < WS_NEED) {  // diagnosable failure: absmax ~12345
    fill_sentinel<<<(out_size + 255) / 256, 256, 0, stream>>>(out, out_size, 12345.0f);
    return;
  }

  u16* xhi = (u16*)(ws + OFF_XHI);
  u16* xlo = (u16*)(ws + OFF_XLO);
  u16* Lcls = (u16*)(ws + OFF_LCLS);
  float* pwe0 = (float*)(ws + OFF_LWE_P0);
  float* pwe1 = (float*)(ws + OFF_LWE_P1);
  float* pwe2 = (float*)(ws + OFF_LWE_P2);
  u16* LewB = (u16*)(ws + OFF_LEWB);
  u16* BT1 = (u16*)(ws + OFF_BT1);
  u16* BTwe_hi = (u16*)(ws + OFF_BTWE_HI);
  u16* BTwe_lo = (u16*)(ws + OFF_BTWE_LO);
  u16* BT2cls = (u16*)(ws + OFF_BT2CLS);
  u16* BT2ew = (u16*)(ws + OFF_BT2EW);
  u16* BT2we_hi = (u16*)(ws + OFF_BT2WE_HI);
  u16* BT2we_lo = (u16*)(ws + OFF_BT2WE_LO);
  float* b1ce = (float*)(ws + OFF_B1CE);
  float* b1we = (float*)(ws + OFF_B1WE);
  float* b2cls = (float*)(ws + OFF_B2CLS);
  float* b2ew = (float*)(ws + OFF_B2EW);
  float* b2we = (float*)(ws + OFF_B2WE);
  u16* h_clsew = (u16*)(ws + OFF_HCLSEW);
  u16* h_we_hi = (u16*)(ws + OFF_HWE_HI);
  u16* h_we_lo = (u16*)(ws + OFF_HWE_LO);

  prep_all<<<13165, 256, 0, stream>>>(x, xhi, xlo,
                                      cls_w1, ew_w1, we_w1, cls_w2, ew_w2, we_w2,
                                      BT1, BTwe_hi, BTwe_lo, BT2cls, BT2ew, BT2we_hi, BT2we_lo,
                                      cls_b1, ew_b1, we_b1, cls_b2, ew_b2, we_b2,
                                      b1ce, b1we, b2cls, b2ew, b2we);
  // fc1 BOTH heads in one dispatch: heavy packed-split we blocks first, cls/ew backfills
  gemm1_fused<<<2304, 256, 0, stream>>>(xhi, xlo, BTwe_hi, BTwe_lo, BT1,
                                        b1we, b1ce, h_we_hi, h_we_lo, h_clsew);
  // fc2: 1280 uniform-or-smaller blocks; last 256 half-unit we-pass blocks backfill the drain
  gemm2_fused<<<1280, 256, 0, stream>>>(h_clsew, h_we_hi, h_we_lo,
                                        BT2cls, BT2ew, BT2we_hi, BT2we_lo,
                                        b2cls, b2ew, b2we,
                                        Lcls, LewB, pwe0, pwe1, pwe2);
  finalize<<<4096, 256, 0, stream>>>(Lcls, pwe0, pwe1, pwe2, LewB, nexp, out);
}